// Round 11
// baseline (435.244 us; speedup 1.0000x reference)
//
#include <hip/hip_runtime.h>
#include <hip/hip_bf16.h>
#include <hip/hip_fp16.h>

#define N_NODES 100000
#define N_EDGES 20000
#define NNZ     1600000
#define D       128
#define STAR    64
#define NEG_SLOPE 0.2f

// edge counting-sort: SINGLE pass, 20000 bins packed as 2xushort per int (40 KB).
#define NBLK_E  400
#define CHUNK_E 4000        // NNZ / NBLK_E
#define H32_E   10000       // ints = 20000 packed ushort bins

// node counting-sort: 5 passes of 20000 packed-ushort bins (40 KB LDS).
#define NBLK_N  64
#define CHUNK_N 25000       // NNZ / NBLK_N
#define BINS_N  20000
#define H32_N   10000
#define NPASS_N 5

// two-level chunk scan: 8 groups for both partitions (== 8 XCDs)
#define NGRP    8
#define CPG_E   (NBLK_E / NGRP)   // 50 chunks per group
#define CPG_N   (NBLK_N / NGRP)   // 8 chunks per group
// incidences per group = CPG_E*CHUNK_E = CPG_N*CHUNK_N = 200000 for both

// scatter grid geometry for XCD-chunked remap
#define SCAT_NWG ((NNZ + 255) / 256)   // 6250
#define SCAT_Q   (SCAT_NWG / 8)        // 781
#define SCAT_R   (SCAT_NWG % 8)        // 2

// multi-block scan: 256 threads x 16 elements
#define SCC 16
#define SC_PER_BLOCK (256 * SCC)   // 4096
#define SC_NBLK(n) (((n) + SC_PER_BLOCK - 1) / SC_PER_BLOCK)

typedef _Float16 half8 __attribute__((ext_vector_type(8)));
typedef float    floatx4 __attribute__((ext_vector_type(4)));

// pack 8 fp32 (two float4) -> half8 fragment
__device__ __forceinline__ half8 cvt8(float4 f0, float4 f1)
{
    half8 h;
    h[0] = (_Float16)f0.x; h[1] = (_Float16)f0.y;
    h[2] = (_Float16)f0.z; h[3] = (_Float16)f0.w;
    h[4] = (_Float16)f1.x; h[5] = (_Float16)f1.y;
    h[6] = (_Float16)f1.z; h[7] = (_Float16)f1.w;
    return h;
}

// ---------------------------------------------------------------------------
// K0: one-time fp32 -> fp16 weight conversion.
// ---------------------------------------------------------------------------
__global__ __launch_bounds__(256) void k_cvt_w(
    const float* __restrict__ Wx, const float* __restrict__ Wv,
    const float* __restrict__ Wt,
    __half* __restrict__ Wf16, __half* __restrict__ Wtf16)
{
    int i = (blockIdx.x * 256 + threadIdx.x) * 4;
    const float* src;
    __half* dst;
    if (i < 16384)            { src = Wx + i;         dst = Wf16 + i; }
    else if (i < 32768)       { src = Wv + (i-16384); dst = Wf16 + i; }
    else if (i < 32768+24576) { src = Wt + (i-32768); dst = Wtf16 + (i-32768); }
    else return;
    float4 f = *(const float4*)src;
    *(__half2*)(dst)     = __floats2half2_rn(f.x, f.y);
    *(__half2*)(dst + 2) = __floats2half2_rn(f.z, f.w);
}

// ---------------------------------------------------------------------------
// K1: fused node GEMM on matrix cores + FUSED SCORE.
//   [X_init | X_feat] = X @ [Wx^T | Wv^T] + bias;  wexp = exp(lrelu(Xf.a))
// ---------------------------------------------------------------------------
__global__ __launch_bounds__(256) void k_node_gemm(
    const float* __restrict__ X, const __half* __restrict__ Wf16,
    const float* __restrict__ Wxb, const float* __restrict__ Wvb,
    const float* __restrict__ aw,
    float* __restrict__ Xinit, __half* __restrict__ Xf16,
    float* __restrict__ wexp)
{
    __shared__ char smem[64 * 256];   // 16 KB A-tile; reused for fp16 repack
    const int tid  = threadIdx.x;
    const int w    = tid >> 6;
    const int lane = tid & 63;
    const int bm   = blockIdx.x * 64;
    const int colbase = w * 64;               // 0,64,128,192
    const bool isInit = (colbase < D);
    const int r16 = lane & 15;
    const int hi  = lane >> 4;                // 0..3
    const int g8  = hi * 8;

    // ---- stage A tile: coalesced fp32 load -> fp16 -> swizzled LDS ----
    {
        const int r  = tid >> 2;              // 0..63
        int srow = bm + r; if (srow >= N_NODES) srow = N_NODES - 1;
        const float4* src = (const float4*)(X + (size_t)srow * D + (tid & 3) * 32);
        float4 f[8];
        #pragma unroll
        for (int j = 0; j < 8; ++j) f[j] = src[j];
        const int swz  = (r & 7) << 4;
        const int base = r * 256 + (tid & 3) * 64;
        #pragma unroll
        for (int j = 0; j < 4; ++j)
            *(half8*)(smem + ((base + j * 16) ^ swz)) = cvt8(f[2*j], f[2*j+1]);
    }

    // ---- hoist all 16 B fragments (fp16, L2-resident) ----
    half8 bf[4][4];
    #pragma unroll
    for (int ks = 0; ks < 4; ++ks)
        #pragma unroll
        for (int n = 0; n < 4; ++n)
            bf[ks][n] = *(const half8*)(Wf16 + (size_t)(colbase + n*16 + r16) * D
                                        + ks * 32 + g8);

    __syncthreads();

    floatx4 acc[4][4] = {};
    #pragma unroll
    for (int ks = 0; ks < 4; ++ks) {
        half8 a[4];
        #pragma unroll
        for (int m = 0; m < 4; ++m) {
            const int R = m * 16 + r16;
            a[m] = *(const half8*)(smem + ((R*256 + ks*64 + hi*16) ^ ((R&7)<<4)));
        }
        #pragma unroll
        for (int m = 0; m < 4; ++m)
            #pragma unroll
            for (int n = 0; n < 4; ++n)
                acc[m][n] = __builtin_amdgcn_mfma_f32_16x16x32_f16(
                    a[m], bf[ks][n], acc[m][n], 0, 0, 0);
    }

    const float* bias = isInit ? Wxb : Wvb;
    const int rq = hi * 4;

    __syncthreads();   // A-tile dead; smem reusable

    if (isInit) {
        #pragma unroll
        for (int n = 0; n < 4; ++n) {
            const int c = (colbase & (D - 1)) + n * 16 + r16;
            const float bv = bias[c];
            #pragma unroll
            for (int m = 0; m < 4; ++m)
                #pragma unroll
                for (int q = 0; q < 4; ++q) {
                    const int row = bm + m * 16 + rq + q;
                    if (row < N_NODES)
                        Xinit[(size_t)row * D + c] = acc[m][n][q] + bv;
                }
        }
    } else {
        __half* sh = (__half*)smem;
        #pragma unroll
        for (int n = 0; n < 4; ++n) {
            const int lc = (colbase - D) + n * 16 + r16;   // 0..127
            const float bv = bias[(colbase & (D - 1)) + n * 16 + r16];
            #pragma unroll
            for (int m = 0; m < 4; ++m)
                #pragma unroll
                for (int q = 0; q < 4; ++q)
                    sh[(m * 16 + rq + q) * 128 + lc] =
                        __float2half(acc[m][n][q] + bv);
        }
    }
    __syncthreads();
    // coalesced Xf16 store + fused score (4 threads per row)
    {
        const int r   = tid >> 2;
        const int row = bm + r;
        const int q4  = tid & 3;
        if (row < N_NODES) {
            const char* src = smem + r * 256 + q4 * 64;
            __half* dst = Xf16 + (size_t)row * D + q4 * 32;
            float part = 0.f;
            #pragma unroll
            for (int j = 0; j < 4; ++j) {
                half8 h = *(const half8*)(src + j * 16);
                *(half8*)(dst + j * 8) = h;
                float4 a0 = *(const float4*)(aw + q4 * 32 + j * 8);
                float4 a1 = *(const float4*)(aw + q4 * 32 + j * 8 + 4);
                part += (float)h[0]*a0.x + (float)h[1]*a0.y
                      + (float)h[2]*a0.z + (float)h[3]*a0.w
                      + (float)h[4]*a1.x + (float)h[5]*a1.y
                      + (float)h[6]*a1.z + (float)h[7]*a1.w;
            }
            part += __shfl_xor(part, 1, 64);
            part += __shfl_xor(part, 2, 64);
            if (q4 == 0) {
                float l = (part > 0.f) ? part : NEG_SLOPE * part;
                wexp[row] = expf(l);
            }
        }
    }
}

// ---------------------------------------------------------------------------
// K3: MERGED histogram+rank kernel. Blocks [0,NBLK_E) do edge chunks
// (single pass, all 20000 bins); blocks [NBLK_E, NBLK_E+NBLK_N*NPASS_N)
// do node (chunk, pass) pairs. Both paths: 40 KB packed-ushort LDS bins,
// rank = halfword of LDS atomicAdd return.
// ---------------------------------------------------------------------------
__global__ __launch_bounds__(256) void k_part_all(
    const int* __restrict__ E, const int* __restrict__ V,
    unsigned short* __restrict__ part_e, unsigned short* __restrict__ part_n,
    unsigned short* __restrict__ re, unsigned short* __restrict__ rn)
{
    __shared__ int h[H32_E];   // 10000 ints = 40 KB (H32_E == H32_N)
    const int blk = blockIdx.x;
    for (int t = threadIdx.x; t < H32_E; t += 256) h[t] = 0;
    __syncthreads();

    if (blk < NBLK_E) {
        const int b = blk;
        const int i0 = b * CHUNK_E;
        const int4* E4 = (const int4*)(E + i0);
        for (int i = threadIdx.x; i < CHUNK_E / 4; i += 256) {
            int4 q = E4[i];
            int ev[4] = {q.x, q.y, q.z, q.w};
            #pragma unroll
            for (int t = 0; t < 4; ++t) {
                int e = ev[t];
                unsigned sh = (e & 1) << 4;
                int old = atomicAdd(&h[e >> 1], 1 << sh);
                re[i0 + i * 4 + t] = (unsigned short)((unsigned)old >> sh);
            }
        }
        __syncthreads();
        int* dst = (int*)(part_e + (size_t)b * N_EDGES);
        for (int t = threadIdx.x; t < H32_E; t += 256) dst[t] = h[t];
    } else {
        const int idx = blk - NBLK_E;        // 0..319
        const int b   = idx & 63;            // node chunk
        const int c0  = (idx >> 6) * BINS_N; // pass * 20000
        const int i0  = b * CHUNK_N;
        const int4* V4 = (const int4*)(V + i0);
        for (int i = threadIdx.x; i < CHUNK_N / 4; i += 256) {
            int4 q = V4[i];
            int vv[4] = {q.x, q.y, q.z, q.w};
            #pragma unroll
            for (int t = 0; t < 4; ++t) {
                int c = vv[t] - c0;
                if ((unsigned)c < (unsigned)BINS_N) {
                    unsigned sh = (c & 1) << 4;
                    int old = atomicAdd(&h[c >> 1], 1 << sh);
                    rn[i0 + i * 4 + t] = (unsigned short)((unsigned)old >> sh);
                }
            }
        }
        __syncthreads();
        int* dst = (int*)(part_n + (size_t)b * N_NODES + c0);
        for (int t = threadIdx.x; t < H32_N; t += 256) dst[t] = h[t];
    }
}

// ---------------------------------------------------------------------------
// K5a: within-GROUP exclusive scan over chunks (level 1 of 2).
// ---------------------------------------------------------------------------
__global__ __launch_bounds__(256) void k_tot_grp(
    unsigned short* __restrict__ part, int* __restrict__ gsum,
    int nbins, int cpg)
{
    int bin = blockIdx.x * 256 + threadIdx.x;
    if (bin >= nbins) return;
    const int g = blockIdx.y;
    int run = 0;
    #pragma unroll 10
    for (int b = g * cpg; b < (g + 1) * cpg; ++b) {
        size_t idx = (size_t)b * nbins + bin;
        int v = part[idx];
        part[idx] = (unsigned short)run;
        run += v;
    }
    gsum[(size_t)g * nbins + bin] = run;
}

// ---------------------------------------------------------------------------
// K5b: exclusive scan over the NGRP group sums (level 2); emits tot.
// ---------------------------------------------------------------------------
__global__ __launch_bounds__(256) void k_tot_fin(
    int* __restrict__ gsum, int* __restrict__ tot, int nbins)
{
    int bin = blockIdx.x * 256 + threadIdx.x;
    if (bin >= nbins) return;
    int run = 0;
    #pragma unroll
    for (int g = 0; g < NGRP; ++g) {
        size_t idx = (size_t)g * nbins + bin;
        int v = gsum[idx];
        gsum[idx] = run;
        run += v;
    }
    tot[bin] = run;
}

// ---------------------------------------------------------------------------
// Multi-block scan, phase 1: per-block sums. 256 thr x 16 elems (int4).
// ---------------------------------------------------------------------------
__global__ __launch_bounds__(256) void k_scan_bsum(
    const int* __restrict__ cnt, int* __restrict__ bsum, int n)
{
    __shared__ int red[256];
    const int base = blockIdx.x * SC_PER_BLOCK + threadIdx.x * SCC;
    int s = 0;
    if (base + SCC <= n) {
        const int4* p4 = (const int4*)(cnt + base);
        #pragma unroll
        for (int j = 0; j < SCC / 4; ++j) {
            int4 v = p4[j];
            s += v.x + v.y + v.z + v.w;
        }
    } else {
        for (int i = base; i < n; ++i) s += cnt[i];
    }
    red[threadIdx.x] = s;
    __syncthreads();
    for (int d = 128; d > 0; d >>= 1) {
        if (threadIdx.x < d) red[threadIdx.x] += red[threadIdx.x + d];
        __syncthreads();
    }
    if (threadIdx.x == 0) bsum[blockIdx.x] = red[0];
}

// ---------------------------------------------------------------------------
// Phase 2: exclusive block bases; writes total into off[n].  nb <= 1024.
// ---------------------------------------------------------------------------
__global__ __launch_bounds__(1024) void k_scan_bbase(
    int* __restrict__ bsum, int nb, int* __restrict__ off, int n)
{
    __shared__ int sums[1024];
    const int tid = threadIdx.x;
    sums[tid] = (tid < nb) ? bsum[tid] : 0;
    __syncthreads();
    for (int d = 1; d < 1024; d <<= 1) {
        int mine = sums[tid];
        int other = (tid >= d) ? sums[tid - d] : 0;
        __syncthreads();
        sums[tid] = mine + other;
        __syncthreads();
    }
    if (tid < nb) bsum[tid] = (tid > 0) ? sums[tid - 1] : 0;
    if (tid == 0) off[n] = sums[1023];
}

// ---------------------------------------------------------------------------
// Phase 3: per-block exclusive scan + block base -> off[i].
// ---------------------------------------------------------------------------
__global__ __launch_bounds__(256) void k_scan_out(
    const int* __restrict__ cnt, const int* __restrict__ bsum,
    int* __restrict__ off, int n)
{
    __shared__ int tsum[256];
    const int base = blockIdx.x * SC_PER_BLOCK + threadIdx.x * SCC;
    int vals[SCC];
    int s = 0;
    if (base + SCC <= n) {
        const int4* p4 = (const int4*)(cnt + base);
        #pragma unroll
        for (int j = 0; j < SCC / 4; ++j) {
            int4 v = p4[j];
            vals[4 * j + 0] = v.x; vals[4 * j + 1] = v.y;
            vals[4 * j + 2] = v.z; vals[4 * j + 3] = v.w;
            s += v.x + v.y + v.z + v.w;
        }
    } else {
        #pragma unroll
        for (int j = 0; j < SCC; ++j) {
            int i = base + j;
            vals[j] = (i < n) ? cnt[i] : 0;
            s += vals[j];
        }
    }
    tsum[threadIdx.x] = s;
    __syncthreads();
    for (int d = 1; d < 256; d <<= 1) {
        int mine = tsum[threadIdx.x];
        int other = (threadIdx.x >= d) ? tsum[threadIdx.x - d] : 0;
        __syncthreads();
        tsum[threadIdx.x] = mine + other;
        __syncthreads();
    }
    int run = bsum[blockIdx.x] + ((threadIdx.x > 0) ? tsum[threadIdx.x - 1] : 0);
    #pragma unroll
    for (int j = 0; j < SCC; ++j) {
        int i = base + j;
        if (i < n) { off[i] = run; run += vals[j]; }
    }
}

// ---------------------------------------------------------------------------
// K6: FUSED flat scatter, XCD-CHUNKED (bid%8 == presumed XCD processes the
// matching contiguous group of incidences so each output line is written
// by ~1 XCD). Correctness is mapping-independent (pure bijection on i).
// ---------------------------------------------------------------------------
__global__ __launch_bounds__(256) void k_scatter_both(
    const int* __restrict__ V, const int* __restrict__ E,
    const unsigned short* __restrict__ re, const unsigned short* __restrict__ rn,
    const unsigned short* __restrict__ part_e,
    const unsigned short* __restrict__ part_n,
    const int* __restrict__ gsum_e, const int* __restrict__ gsum_n,
    const int* __restrict__ eoff, const int* __restrict__ noff,
    int* __restrict__ epairs, unsigned short* __restrict__ nedges)
{
    const int bid = blockIdx.x;
    const int xcd = bid & 7;
    const int j   = bid >> 3;
    const int vb  = (xcd < SCAT_R) ? xcd * (SCAT_Q + 1) + j
                                   : SCAT_R * (SCAT_Q + 1) + (xcd - SCAT_R) * SCAT_Q + j;
    int i = vb * 256 + (int)threadIdx.x;
    if (i >= NNZ) return;
    int e = E[i], v = V[i];
    int be = i / CHUNK_E;
    int bn = i / CHUNK_N;
    int g  = i / 200000;            // = be/CPG_E = bn/CPG_N
    int pe = eoff[e] + gsum_e[(size_t)g * N_EDGES + e]
                     + part_e[(size_t)be * N_EDGES + e] + re[i];
    int pn = noff[v] + gsum_n[(size_t)g * N_NODES + v]
                     + part_n[(size_t)bn * N_NODES + v] + rn[i];
    epairs[pe] = v;
    nedges[pn] = (unsigned short)e;
}

// ---------------------------------------------------------------------------
// helper: accumulate 8 dims (8 halves packed in a float4) with weight w
// ---------------------------------------------------------------------------
__device__ __forceinline__ void acc8h(float w, float4 raw, float (&a)[8])
{
    const __half2* h = (const __half2*)&raw;
    #pragma unroll
    for (int t = 0; t < 4; ++t) {
        float2 f = __half22float2(h[t]);
        a[2*t]   = fmaf(w, f.x, a[2*t]);
        a[2*t+1] = fmaf(w, f.y, a[2*t+1]);
    }
}

// ---------------------------------------------------------------------------
// K8: per-edge aggregation. ONE WAVE PER EDGE, FOUR 16-LANE SLOTS.
// w gathered from the 400 KB L2-resident wexp table (epairs is v-only).
// fp32 accumulation (weighted; precision-critical through softmax).
// ---------------------------------------------------------------------------
__global__ __launch_bounds__(256) void k_edge_agg(
    const int* __restrict__ epairs, const int* __restrict__ eoff,
    const float* __restrict__ wexp,
    const __half* __restrict__ Xf16, const float* __restrict__ S,
    float* __restrict__ emsg)
{
    const int wave = threadIdx.x >> 6, lane = threadIdx.x & 63;
    const int e = blockIdx.x * 4 + wave;
    if (e >= N_EDGES) return;
    const int beg = eoff[e], end = eoff[e + 1];
    const int slot = lane >> 4;          // 0..3
    const int sl = lane & 15;            // dims 8*sl .. 8*sl+7
    float a[8] = {};
    float dsum = 0.f;
    int j = beg;
    #pragma unroll 2
    for (; j + 3 < end; j += 4) {
        int v = epairs[j + slot];
        float w = wexp[v];
        float4 r = *(const float4*)(Xf16 + (size_t)v * D + sl * 8);
        dsum += w;
        acc8h(w, r, a);
    }
    if (j + slot < end) {
        int v = epairs[j + slot];
        float w = wexp[v];
        float4 r = *(const float4*)(Xf16 + (size_t)v * D + sl * 8);
        dsum += w;
        acc8h(w, r, a);
    }
    #pragma unroll
    for (int k = 0; k < 8; ++k) {
        a[k] += __shfl_xor(a[k], 16, 64);
        a[k] += __shfl_xor(a[k], 32, 64);
    }
    dsum += __shfl_xor(dsum, 16, 64);
    dsum += __shfl_xor(dsum, 32, 64);

    float inv = (end > beg) ? 1.f / dsum : 0.f;
    float y[8];
    #pragma unroll
    for (int k = 0; k < 8; ++k) {
        float t = a[k] * inv;
        y[k] = (t > 0.f) ? t : expm1f(t);
    }
    const size_t rb = (size_t)e * (D + STAR);
    if (slot == 0) {
        *(float4*)(emsg + rb + sl * 8)     = make_float4(y[0], y[1], y[2], y[3]);
        *(float4*)(emsg + rb + sl * 8 + 4) = make_float4(y[4], y[5], y[6], y[7]);
    } else if (slot == 1) {
        float4 s4 = *(const float4*)(S + (size_t)e * STAR + sl * 4);
        *(float4*)(emsg + rb + D + sl * 4) = s4;
    }
}

// ---------------------------------------------------------------------------
// K9: edge GEMM on matrix cores: Y = e_msg @ Wt^T + Wt_b -> fp16.
// ---------------------------------------------------------------------------
__global__ __launch_bounds__(256) void k_edge_gemm(
    const float* __restrict__ A, const __half* __restrict__ Wtf16,
    const float* __restrict__ Wtb, __half* __restrict__ Y16)
{
    __shared__ char smem[64 * 384];   // 24 KB A-tile; head reused for repack
    const int KDIM = D + STAR;        // 192
    const int tid  = threadIdx.x;
    const int w    = tid >> 6;
    const int lane = tid & 63;
    const int bm   = blockIdx.x * 64;
    const int colbase = w * 32;       // 0,32,64,96
    const int r16 = lane & 15;
    const int hi  = lane >> 4;
    const int g8  = hi * 8;

    {
        const int r = tid >> 2;
        int srow = bm + r; if (srow >= N_EDGES) srow = N_EDGES - 1;
        const float4* src = (const float4*)(A + (size_t)srow * KDIM + (tid & 3) * 48);
        float4 f[12];
        #pragma unroll
        for (int j = 0; j < 12; ++j) f[j] = src[j];
        const int swz  = (r & 7) << 4;
        const int base = r * 384 + (tid & 3) * 96;
        #pragma unroll
        for (int j = 0; j < 6; ++j)
            *(half8*)(smem + ((base + j * 16) ^ swz)) = cvt8(f[2*j], f[2*j+1]);
    }

    half8 bf[6][2];
    #pragma unroll
    for (int ks = 0; ks < 6; ++ks)
        #pragma unroll
        for (int n = 0; n < 2; ++n)
            bf[ks][n] = *(const half8*)(Wtf16 + (size_t)(colbase + n*16 + r16) * KDIM
                                        + ks * 32 + g8);

    __syncthreads();

    floatx4 acc[4][2] = {};
    #pragma unroll
    for (int ks = 0; ks < 6; ++ks) {
        half8 a[4];
        #pragma unroll
        for (int m = 0; m < 4; ++m) {
            const int R = m * 16 + r16;
            a[m] = *(const half8*)(smem + ((R*384 + ks*64 + hi*16) ^ ((R&7)<<4)));
        }
        #pragma unroll
        for (int m = 0; m < 4; ++m)
            #pragma unroll
            for (int n = 0; n < 2; ++n)
                acc[m][n] = __builtin_amdgcn_mfma_f32_16x16x32_f16(
                    a[m], bf[ks][n], acc[m][n], 0, 0, 0);
    }

    const int rq = hi * 4;
    __syncthreads();   // A-tile dead

    {
        __half* sh = (__half*)smem;
        #pragma unroll
        for (int n = 0; n < 2; ++n) {
            const int c = colbase + n * 16 + r16;     // 0..127
            const float bv = Wtb[c];
            #pragma unroll
            for (int m = 0; m < 4; ++m)
                #pragma unroll
                for (int q = 0; q < 4; ++q)
                    sh[(m * 16 + rq + q) * 128 + c] =
                        __float2half(acc[m][n][q] + bv);
        }
    }
    __syncthreads();
    {
        const int r   = tid >> 2;
        const int row = bm + r;
        if (row < N_EDGES) {
            const char* src = smem + r * 256 + (tid & 3) * 64;
            __half* dst = Y16 + (size_t)row * D + (tid & 3) * 32;
            #pragma unroll
            for (int j = 0; j < 4; ++j)
                *(half8*)(dst + j * 8) = *(const half8*)(src + j * 16);
        }
    }
}

// ---------------------------------------------------------------------------
// K10: per-node aggregation. ONE WAVE PER NODE, FOUR 16-LANE SLOTS.
// PACKED-FP16 accumulation (v_pk_add_f16): w==1 so the sum is unweighted;
// 4 pk_adds per 8 dims replaces 8 cvt + 8 add -> cuts the VALU-bound loop
// (round-9 counters: VALUBusy 92%). Error after /cnt mean: ~1e-3 << 0.0156.
// out[v] = elu(mean_j Y[e_j]) + out[v]   (out holds X_init).
// ---------------------------------------------------------------------------
__global__ __launch_bounds__(256) void k_node_agg(
    const unsigned short* __restrict__ nedges, const int* __restrict__ noff,
    const __half* __restrict__ Y16, float* __restrict__ out)
{
    const int wave = threadIdx.x >> 6, lane = threadIdx.x & 63;
    const int v = blockIdx.x * 4 + wave;
    if (v >= N_NODES) return;
    const int beg = noff[v], end = noff[v + 1];
    const int slot = lane >> 4;
    const int sl = lane & 15;
    __half2 a2[4];
    #pragma unroll
    for (int t = 0; t < 4; ++t) a2[t] = __half2(__float2half(0.f), __float2half(0.f));
    int j = beg;
    #pragma unroll 2
    for (; j + 3 < end; j += 4) {
        int e0 = nedges[j + slot];
        float4 r = *(const float4*)(Y16 + (size_t)e0 * D + sl * 8);
        const __half2* h = (const __half2*)&r;
        #pragma unroll
        for (int t = 0; t < 4; ++t) a2[t] = __hadd2(a2[t], h[t]);
    }
    if (j + slot < end) {
        int e0 = nedges[j + slot];
        float4 r = *(const float4*)(Y16 + (size_t)e0 * D + sl * 8);
        const __half2* h = (const __half2*)&r;
        #pragma unroll
        for (int t = 0; t < 4; ++t) a2[t] = __hadd2(a2[t], h[t]);
    }
    // cross-slot packed reduction (shuffle the half2 as 32-bit)
    #pragma unroll
    for (int t = 0; t < 4; ++t) {
        int x = __shfl_xor(*(int*)&a2[t], 16, 64);
        a2[t] = __hadd2(a2[t], *(__half2*)&x);
        x = __shfl_xor(*(int*)&a2[t], 32, 64);
        a2[t] = __hadd2(a2[t], *(__half2*)&x);
    }

    if (slot == 0) {
        int cnt = end - beg;
        float invc = 1.f / (float)max(cnt, 1);
        float x[8];
        #pragma unroll
        for (int t = 0; t < 4; ++t) {
            float2 f = __half22float2(a2[t]);
            float t0 = f.x * invc, t1 = f.y * invc;
            x[2*t]   = (t0 > 0.f) ? t0 : expm1f(t0);
            x[2*t+1] = (t1 > 0.f) ? t1 : expm1f(t1);
        }
        float4* o0 = (float4*)(out + (size_t)v * D + sl * 8);
        float4* o1 = (float4*)(out + (size_t)v * D + sl * 8 + 4);
        float4 c0 = *o0, c1 = *o1;
        *o0 = make_float4(c0.x + x[0], c0.y + x[1], c0.z + x[2], c0.w + x[3]);
        *o1 = make_float4(c1.x + x[4], c1.y + x[5], c1.z + x[6], c1.w + x[7]);
    }
}

// ---------------------------------------------------------------------------
extern "C" void kernel_launch(void* const* d_in, const int* in_sizes, int n_in,
                              void* d_out, int out_size, void* d_ws, size_t ws_size,
                              hipStream_t stream)
{
    const float* X    = (const float*)d_in[0];
    const int*   V    = (const int*)  d_in[1];
    const int*   E    = (const int*)  d_in[2];
    const float* S    = (const float*)d_in[3];
    const float* Wx_w = (const float*)d_in[4];
    const float* Wx_b = (const float*)d_in[5];
    const float* Wv_w = (const float*)d_in[6];
    const float* Wv_b = (const float*)d_in[7];
    const float* a_w  = (const float*)d_in[8];
    const float* Wt_w = (const float*)d_in[9];
    const float* Wt_b = (const float*)d_in[10];
    float* out = (float*)d_out;

    char* p = (char*)d_ws;
    auto take = [&](size_t bytes) -> char* {
        char* r = p;
        p += (bytes + 255) & ~(size_t)255;
        return r;
    };

    __half* Xf16  = (__half*)take((size_t)N_NODES * D * 2);
    float*  wexp  = (float*) take((size_t)N_NODES * 4);
    unsigned short* part_e = (unsigned short*)take((size_t)NBLK_E * N_EDGES * 2);
    unsigned short* part_n = (unsigned short*)take((size_t)NBLK_N * N_NODES * 2);
    int*    gsum_e = (int*)  take((size_t)NGRP * N_EDGES * 4);
    int*    gsum_n = (int*)  take((size_t)NGRP * N_NODES * 4);
    int*    tot_e = (int*)   take((size_t)N_EDGES * 4);
    int*    tot_n = (int*)   take((size_t)N_NODES * 4);
    int*    eoff  = (int*)   take((size_t)(N_EDGES + 1) * 4);
    int*    noff  = (int*)   take((size_t)(N_NODES + 1) * 4);
    int*    bsum_e = (int*)  take((size_t)SC_NBLK(N_EDGES) * 4);
    int*    bsum_n = (int*)  take((size_t)SC_NBLK(N_NODES) * 4);
    unsigned short* re = (unsigned short*)take((size_t)NNZ * 2);
    unsigned short* rn = (unsigned short*)take((size_t)NNZ * 2);
    int*    epairs = (int*)  take((size_t)NNZ * 4);
    unsigned short* nedges = (unsigned short*)take((size_t)NNZ * 2);
    float*  emsg  = (float*) take((size_t)N_EDGES * (D + STAR) * 4);
    __half* Y16   = (__half*)take((size_t)N_EDGES * D * 2);
    __half* Wf16  = (__half*)take((size_t)256 * D * 2);          // [Wx;Wv] fp16
    __half* Wtf16 = (__half*)take((size_t)D * (D + STAR) * 2);   // Wt fp16

    k_cvt_w<<<56, 256, 0, stream>>>(Wx_w, Wv_w, Wt_w, Wf16, Wtf16);

    k_node_gemm<<<(N_NODES + 63) / 64, 256, 0, stream>>>(
        X, Wf16, Wx_b, Wv_b, a_w, out, Xf16, wexp);

    k_part_all<<<NBLK_E + NBLK_N * NPASS_N, 256, 0, stream>>>(
        E, V, part_e, part_n, re, rn);

    // two-level chunk scans (8 groups each)
    k_tot_grp<<<dim3((N_EDGES + 255) / 256, NGRP), 256, 0, stream>>>(
        part_e, gsum_e, N_EDGES, CPG_E);
    k_tot_grp<<<dim3((N_NODES + 255) / 256, NGRP), 256, 0, stream>>>(
        part_n, gsum_n, N_NODES, CPG_N);
    k_tot_fin<<<(N_EDGES + 255) / 256, 256, 0, stream>>>(gsum_e, tot_e, N_EDGES);
    k_tot_fin<<<(N_NODES + 255) / 256, 256, 0, stream>>>(gsum_n, tot_n, N_NODES);

    // edge scan (n = 20000, 5 blocks)
    k_scan_bsum<<<SC_NBLK(N_EDGES), 256, 0, stream>>>(tot_e, bsum_e, N_EDGES);
    k_scan_bbase<<<1, 1024, 0, stream>>>(bsum_e, SC_NBLK(N_EDGES), eoff, N_EDGES);
    k_scan_out<<<SC_NBLK(N_EDGES), 256, 0, stream>>>(tot_e, bsum_e, eoff, N_EDGES);

    // node scan (n = 100000, 25 blocks)
    k_scan_bsum<<<SC_NBLK(N_NODES), 256, 0, stream>>>(tot_n, bsum_n, N_NODES);
    k_scan_bbase<<<1, 1024, 0, stream>>>(bsum_n, SC_NBLK(N_NODES), noff, N_NODES);
    k_scan_out<<<SC_NBLK(N_NODES), 256, 0, stream>>>(tot_n, bsum_n, noff, N_NODES);

    k_scatter_both<<<SCAT_NWG, 256, 0, stream>>>(
        V, E, re, rn, part_e, part_n, gsum_e, gsum_n,
        eoff, noff, epairs, nedges);

    k_edge_agg<<<(N_EDGES + 3) / 4, 256, 0, stream>>>(
        epairs, eoff, wexp, Xf16, S, emsg);

    k_edge_gemm<<<(N_EDGES + 63) / 64, 256, 0, stream>>>(emsg, Wtf16, Wt_b, Y16);

    k_node_agg<<<(N_NODES + 3) / 4, 256, 0, stream>>>(nedges, noff, Y16, out);
}

// Round 12
// 399.539 us; speedup vs baseline: 1.0894x; 1.0894x over previous
//
#include <hip/hip_runtime.h>
#include <hip/hip_bf16.h>
#include <hip/hip_fp16.h>

#define N_NODES 100000
#define N_EDGES 20000
#define NNZ     1600000
#define D       128
#define STAR    64
#define NEG_SLOPE 0.2f

// edge counting-sort: SINGLE pass, 20000 bins packed as 2xushort per int (40 KB).
#define NBLK_E  400
#define CHUNK_E 4000        // NNZ / NBLK_E
#define H32_E   10000       // ints = 20000 packed ushort bins

// node counting-sort: 5 passes of 20000 packed-ushort bins (40 KB LDS).
#define NBLK_N  64
#define CHUNK_N 25000       // NNZ / NBLK_N
#define BINS_N  20000
#define H32_N   10000
#define NPASS_N 5

// two-level chunk scan: 8 groups for both partitions (== 8 XCDs)
#define NGRP    8
#define CPG_E   (NBLK_E / NGRP)   // 50 chunks per group
#define CPG_N   (NBLK_N / NGRP)   // 8 chunks per group
// incidences per group = CPG_E*CHUNK_E = CPG_N*CHUNK_N = 200000 for both

// scatter grid geometry for XCD-chunked remap
#define SCAT_NWG ((NNZ + 255) / 256)   // 6250
#define SCAT_Q   (SCAT_NWG / 8)        // 781
#define SCAT_R   (SCAT_NWG % 8)        // 2

// merged scan-pipeline grids
#define TGB_E ((N_EDGES + 255) / 256)   // 79  bin-blocks (edge)
#define TGB_N ((N_NODES + 255) / 256)   // 391 bin-blocks (node)

// multi-block scan: 256 threads x 16 elements
#define SCC 16
#define SC_PER_BLOCK (256 * SCC)   // 4096
#define SCB_E ((N_EDGES + SC_PER_BLOCK - 1) / SC_PER_BLOCK)   // 5
#define SCB_N ((N_NODES + SC_PER_BLOCK - 1) / SC_PER_BLOCK)   // 25

typedef _Float16 half8 __attribute__((ext_vector_type(8)));
typedef float    floatx4 __attribute__((ext_vector_type(4)));

// fast elu: expm1 via v_exp (abs err ~1e-7, fine at 1.6e-2 tolerance)
__device__ __forceinline__ float elu_fast(float t)
{
    return (t > 0.f) ? t : (__expf(t) - 1.f);
}

// pack 8 fp32 (two float4) -> half8 fragment
__device__ __forceinline__ half8 cvt8(float4 f0, float4 f1)
{
    half8 h;
    h[0] = (_Float16)f0.x; h[1] = (_Float16)f0.y;
    h[2] = (_Float16)f0.z; h[3] = (_Float16)f0.w;
    h[4] = (_Float16)f1.x; h[5] = (_Float16)f1.y;
    h[6] = (_Float16)f1.z; h[7] = (_Float16)f1.w;
    return h;
}

// ---------------------------------------------------------------------------
// K0: one-time fp32 -> fp16 weight conversion.
// ---------------------------------------------------------------------------
__global__ __launch_bounds__(256) void k_cvt_w(
    const float* __restrict__ Wx, const float* __restrict__ Wv,
    const float* __restrict__ Wt,
    __half* __restrict__ Wf16, __half* __restrict__ Wtf16)
{
    int i = (blockIdx.x * 256 + threadIdx.x) * 4;
    const float* src;
    __half* dst;
    if (i < 16384)            { src = Wx + i;         dst = Wf16 + i; }
    else if (i < 32768)       { src = Wv + (i-16384); dst = Wf16 + i; }
    else if (i < 32768+24576) { src = Wt + (i-32768); dst = Wtf16 + (i-32768); }
    else return;
    float4 f = *(const float4*)src;
    *(__half2*)(dst)     = __floats2half2_rn(f.x, f.y);
    *(__half2*)(dst + 2) = __floats2half2_rn(f.z, f.w);
}

// ---------------------------------------------------------------------------
// K1: fused node GEMM on matrix cores + FUSED SCORE.
//   [X_init | X_feat] = X @ [Wx^T | Wv^T] + bias;  wexp = exp(lrelu(Xf.a))
// ---------------------------------------------------------------------------
__global__ __launch_bounds__(256) void k_node_gemm(
    const float* __restrict__ X, const __half* __restrict__ Wf16,
    const float* __restrict__ Wxb, const float* __restrict__ Wvb,
    const float* __restrict__ aw,
    float* __restrict__ Xinit, __half* __restrict__ Xf16,
    float* __restrict__ wexp)
{
    __shared__ char smem[64 * 256];   // 16 KB A-tile; reused for fp16 repack
    const int tid  = threadIdx.x;
    const int w    = tid >> 6;
    const int lane = tid & 63;
    const int bm   = blockIdx.x * 64;
    const int colbase = w * 64;               // 0,64,128,192
    const bool isInit = (colbase < D);
    const int r16 = lane & 15;
    const int hi  = lane >> 4;                // 0..3
    const int g8  = hi * 8;

    // ---- stage A tile: coalesced fp32 load -> fp16 -> swizzled LDS ----
    {
        const int r  = tid >> 2;              // 0..63
        int srow = bm + r; if (srow >= N_NODES) srow = N_NODES - 1;
        const float4* src = (const float4*)(X + (size_t)srow * D + (tid & 3) * 32);
        float4 f[8];
        #pragma unroll
        for (int j = 0; j < 8; ++j) f[j] = src[j];
        const int swz  = (r & 7) << 4;
        const int base = r * 256 + (tid & 3) * 64;
        #pragma unroll
        for (int j = 0; j < 4; ++j)
            *(half8*)(smem + ((base + j * 16) ^ swz)) = cvt8(f[2*j], f[2*j+1]);
    }

    // ---- hoist all 16 B fragments (fp16, L2-resident) ----
    half8 bf[4][4];
    #pragma unroll
    for (int ks = 0; ks < 4; ++ks)
        #pragma unroll
        for (int n = 0; n < 4; ++n)
            bf[ks][n] = *(const half8*)(Wf16 + (size_t)(colbase + n*16 + r16) * D
                                        + ks * 32 + g8);

    __syncthreads();

    floatx4 acc[4][4] = {};
    #pragma unroll
    for (int ks = 0; ks < 4; ++ks) {
        half8 a[4];
        #pragma unroll
        for (int m = 0; m < 4; ++m) {
            const int R = m * 16 + r16;
            a[m] = *(const half8*)(smem + ((R*256 + ks*64 + hi*16) ^ ((R&7)<<4)));
        }
        #pragma unroll
        for (int m = 0; m < 4; ++m)
            #pragma unroll
            for (int n = 0; n < 4; ++n)
                acc[m][n] = __builtin_amdgcn_mfma_f32_16x16x32_f16(
                    a[m], bf[ks][n], acc[m][n], 0, 0, 0);
    }

    const float* bias = isInit ? Wxb : Wvb;
    const int rq = hi * 4;

    __syncthreads();   // A-tile dead; smem reusable

    if (isInit) {
        #pragma unroll
        for (int n = 0; n < 4; ++n) {
            const int c = (colbase & (D - 1)) + n * 16 + r16;
            const float bv = bias[c];
            #pragma unroll
            for (int m = 0; m < 4; ++m)
                #pragma unroll
                for (int q = 0; q < 4; ++q) {
                    const int row = bm + m * 16 + rq + q;
                    if (row < N_NODES)
                        Xinit[(size_t)row * D + c] = acc[m][n][q] + bv;
                }
        }
    } else {
        __half* sh = (__half*)smem;
        #pragma unroll
        for (int n = 0; n < 4; ++n) {
            const int lc = (colbase - D) + n * 16 + r16;   // 0..127
            const float bv = bias[(colbase & (D - 1)) + n * 16 + r16];
            #pragma unroll
            for (int m = 0; m < 4; ++m)
                #pragma unroll
                for (int q = 0; q < 4; ++q)
                    sh[(m * 16 + rq + q) * 128 + lc] =
                        __float2half(acc[m][n][q] + bv);
        }
    }
    __syncthreads();
    // coalesced Xf16 store + fused score (4 threads per row)
    {
        const int r   = tid >> 2;
        const int row = bm + r;
        const int q4  = tid & 3;
        if (row < N_NODES) {
            const char* src = smem + r * 256 + q4 * 64;
            __half* dst = Xf16 + (size_t)row * D + q4 * 32;
            float part = 0.f;
            #pragma unroll
            for (int j = 0; j < 4; ++j) {
                half8 h = *(const half8*)(src + j * 16);
                *(half8*)(dst + j * 8) = h;
                float4 a0 = *(const float4*)(aw + q4 * 32 + j * 8);
                float4 a1 = *(const float4*)(aw + q4 * 32 + j * 8 + 4);
                part += (float)h[0]*a0.x + (float)h[1]*a0.y
                      + (float)h[2]*a0.z + (float)h[3]*a0.w
                      + (float)h[4]*a1.x + (float)h[5]*a1.y
                      + (float)h[6]*a1.z + (float)h[7]*a1.w;
            }
            part += __shfl_xor(part, 1, 64);
            part += __shfl_xor(part, 2, 64);
            if (q4 == 0) {
                float l = (part > 0.f) ? part : NEG_SLOPE * part;
                wexp[row] = expf(l);
            }
        }
    }
}

// ---------------------------------------------------------------------------
// K3: MERGED histogram+rank kernel (edge single-pass + node 5-pass),
// 40 KB packed-ushort LDS bins, rank = halfword of LDS atomicAdd return.
// ---------------------------------------------------------------------------
__global__ __launch_bounds__(256) void k_part_all(
    const int* __restrict__ E, const int* __restrict__ V,
    unsigned short* __restrict__ part_e, unsigned short* __restrict__ part_n,
    unsigned short* __restrict__ re, unsigned short* __restrict__ rn)
{
    __shared__ int h[H32_E];   // 10000 ints = 40 KB (H32_E == H32_N)
    const int blk = blockIdx.x;
    for (int t = threadIdx.x; t < H32_E; t += 256) h[t] = 0;
    __syncthreads();

    if (blk < NBLK_E) {
        const int b = blk;
        const int i0 = b * CHUNK_E;
        const int4* E4 = (const int4*)(E + i0);
        for (int i = threadIdx.x; i < CHUNK_E / 4; i += 256) {
            int4 q = E4[i];
            int ev[4] = {q.x, q.y, q.z, q.w};
            #pragma unroll
            for (int t = 0; t < 4; ++t) {
                int e = ev[t];
                unsigned sh = (e & 1) << 4;
                int old = atomicAdd(&h[e >> 1], 1 << sh);
                re[i0 + i * 4 + t] = (unsigned short)((unsigned)old >> sh);
            }
        }
        __syncthreads();
        int* dst = (int*)(part_e + (size_t)b * N_EDGES);
        for (int t = threadIdx.x; t < H32_E; t += 256) dst[t] = h[t];
    } else {
        const int idx = blk - NBLK_E;        // 0..319
        const int b   = idx & 63;            // node chunk
        const int c0  = (idx >> 6) * BINS_N; // pass * 20000
        const int i0  = b * CHUNK_N;
        const int4* V4 = (const int4*)(V + i0);
        for (int i = threadIdx.x; i < CHUNK_N / 4; i += 256) {
            int4 q = V4[i];
            int vv[4] = {q.x, q.y, q.z, q.w};
            #pragma unroll
            for (int t = 0; t < 4; ++t) {
                int c = vv[t] - c0;
                if ((unsigned)c < (unsigned)BINS_N) {
                    unsigned sh = (c & 1) << 4;
                    int old = atomicAdd(&h[c >> 1], 1 << sh);
                    rn[i0 + i * 4 + t] = (unsigned short)((unsigned)old >> sh);
                }
            }
        }
        __syncthreads();
        int* dst = (int*)(part_n + (size_t)b * N_NODES + c0);
        for (int t = threadIdx.x; t < H32_N; t += 256) dst[t] = h[t];
    }
}

// ---------------------------------------------------------------------------
// K5a: MERGED within-group scan (edge blocks [0,79), node [79,470)).
// ---------------------------------------------------------------------------
__global__ __launch_bounds__(256) void k_tot_grp2(
    unsigned short* __restrict__ part_e, int* __restrict__ gsum_e,
    unsigned short* __restrict__ part_n, int* __restrict__ gsum_n)
{
    const int g = blockIdx.y;
    unsigned short* part; int* gsum; int nbins, cpg, bin;
    if (blockIdx.x < TGB_E) {
        bin = blockIdx.x * 256 + threadIdx.x;
        part = part_e; gsum = gsum_e; nbins = N_EDGES; cpg = CPG_E;
    } else {
        bin = (blockIdx.x - TGB_E) * 256 + threadIdx.x;
        part = part_n; gsum = gsum_n; nbins = N_NODES; cpg = CPG_N;
    }
    if (bin >= nbins) return;
    int run = 0;
    #pragma unroll 8
    for (int b = g * cpg; b < (g + 1) * cpg; ++b) {
        size_t idx = (size_t)b * nbins + bin;
        int v = part[idx];
        part[idx] = (unsigned short)run;
        run += v;
    }
    gsum[(size_t)g * nbins + bin] = run;
}

// ---------------------------------------------------------------------------
// K5b: MERGED exclusive scan over the NGRP group sums; emits tot.
// ---------------------------------------------------------------------------
__global__ __launch_bounds__(256) void k_tot_fin2(
    int* __restrict__ gsum_e, int* __restrict__ tot_e,
    int* __restrict__ gsum_n, int* __restrict__ tot_n)
{
    int* gsum; int* tot; int nbins, bin;
    if (blockIdx.x < TGB_E) {
        bin = blockIdx.x * 256 + threadIdx.x;
        gsum = gsum_e; tot = tot_e; nbins = N_EDGES;
    } else {
        bin = (blockIdx.x - TGB_E) * 256 + threadIdx.x;
        gsum = gsum_n; tot = tot_n; nbins = N_NODES;
    }
    if (bin >= nbins) return;
    int run = 0;
    #pragma unroll
    for (int g = 0; g < NGRP; ++g) {
        size_t idx = (size_t)g * nbins + bin;
        int v = gsum[idx];
        gsum[idx] = run;
        run += v;
    }
    tot[bin] = run;
}

// ---------------------------------------------------------------------------
// MERGED multi-block scan phase 1: edge blocks [0,5), node [5,30).
// ---------------------------------------------------------------------------
__global__ __launch_bounds__(256) void k_scan_bsum2(
    const int* __restrict__ tot_e, int* __restrict__ bsum_e,
    const int* __restrict__ tot_n, int* __restrict__ bsum_n)
{
    __shared__ int red[256];
    const int* cnt; int* bsum; int n, blk;
    if (blockIdx.x < SCB_E) { cnt = tot_e; bsum = bsum_e; n = N_EDGES; blk = blockIdx.x; }
    else { cnt = tot_n; bsum = bsum_n; n = N_NODES; blk = blockIdx.x - SCB_E; }
    const int base = blk * SC_PER_BLOCK + threadIdx.x * SCC;
    int s = 0;
    if (base + SCC <= n) {
        const int4* p4 = (const int4*)(cnt + base);
        #pragma unroll
        for (int j = 0; j < SCC / 4; ++j) {
            int4 v = p4[j];
            s += v.x + v.y + v.z + v.w;
        }
    } else {
        for (int i = base; i < n; ++i) s += cnt[i];
    }
    red[threadIdx.x] = s;
    __syncthreads();
    for (int d = 128; d > 0; d >>= 1) {
        if (threadIdx.x < d) red[threadIdx.x] += red[threadIdx.x + d];
        __syncthreads();
    }
    if (threadIdx.x == 0) bsum[blk] = red[0];
}

// ---------------------------------------------------------------------------
// MERGED phase 2 (block 0 = edge, block 1 = node): exclusive block bases,
// writes total into off[n].
// ---------------------------------------------------------------------------
__global__ __launch_bounds__(1024) void k_scan_bbase2(
    int* __restrict__ bsum_e, int* __restrict__ eoff,
    int* __restrict__ bsum_n, int* __restrict__ noff)
{
    __shared__ int sums[1024];
    int* bsum; int* off; int nb, n;
    if (blockIdx.x == 0) { bsum = bsum_e; off = eoff; nb = SCB_E; n = N_EDGES; }
    else                 { bsum = bsum_n; off = noff; nb = SCB_N; n = N_NODES; }
    const int tid = threadIdx.x;
    sums[tid] = (tid < nb) ? bsum[tid] : 0;
    __syncthreads();
    for (int d = 1; d < 1024; d <<= 1) {
        int mine = sums[tid];
        int other = (tid >= d) ? sums[tid - d] : 0;
        __syncthreads();
        sums[tid] = mine + other;
        __syncthreads();
    }
    if (tid < nb) bsum[tid] = (tid > 0) ? sums[tid - 1] : 0;
    if (tid == 0) off[n] = sums[1023];
}

// ---------------------------------------------------------------------------
// MERGED phase 3: per-block exclusive scan + block base -> off[i].
// ---------------------------------------------------------------------------
__global__ __launch_bounds__(256) void k_scan_out2(
    const int* __restrict__ tot_e, const int* __restrict__ bsum_e,
    int* __restrict__ eoff,
    const int* __restrict__ tot_n, const int* __restrict__ bsum_n,
    int* __restrict__ noff)
{
    __shared__ int tsum[256];
    const int* cnt; const int* bsum; int* off; int n, blk;
    if (blockIdx.x < SCB_E) {
        cnt = tot_e; bsum = bsum_e; off = eoff; n = N_EDGES; blk = blockIdx.x;
    } else {
        cnt = tot_n; bsum = bsum_n; off = noff; n = N_NODES; blk = blockIdx.x - SCB_E;
    }
    const int base = blk * SC_PER_BLOCK + threadIdx.x * SCC;
    int vals[SCC];
    int s = 0;
    if (base + SCC <= n) {
        const int4* p4 = (const int4*)(cnt + base);
        #pragma unroll
        for (int j = 0; j < SCC / 4; ++j) {
            int4 v = p4[j];
            vals[4 * j + 0] = v.x; vals[4 * j + 1] = v.y;
            vals[4 * j + 2] = v.z; vals[4 * j + 3] = v.w;
            s += v.x + v.y + v.z + v.w;
        }
    } else {
        #pragma unroll
        for (int j = 0; j < SCC; ++j) {
            int i = base + j;
            vals[j] = (i < n) ? cnt[i] : 0;
            s += vals[j];
        }
    }
    tsum[threadIdx.x] = s;
    __syncthreads();
    for (int d = 1; d < 256; d <<= 1) {
        int mine = tsum[threadIdx.x];
        int other = (threadIdx.x >= d) ? tsum[threadIdx.x - d] : 0;
        __syncthreads();
        tsum[threadIdx.x] = mine + other;
        __syncthreads();
    }
    int run = bsum[blk] + ((threadIdx.x > 0) ? tsum[threadIdx.x - 1] : 0);
    #pragma unroll
    for (int j = 0; j < SCC; ++j) {
        int i = base + j;
        if (i < n) { off[i] = run; run += vals[j]; }
    }
}

// ---------------------------------------------------------------------------
// K6: FUSED flat scatter, XCD-CHUNKED (bid%8 == presumed XCD processes the
// matching contiguous group of incidences so each output line is written
// by ~1 XCD). Correctness is mapping-independent (pure bijection on i).
// ---------------------------------------------------------------------------
__global__ __launch_bounds__(256) void k_scatter_both(
    const int* __restrict__ V, const int* __restrict__ E,
    const unsigned short* __restrict__ re, const unsigned short* __restrict__ rn,
    const unsigned short* __restrict__ part_e,
    const unsigned short* __restrict__ part_n,
    const int* __restrict__ gsum_e, const int* __restrict__ gsum_n,
    const int* __restrict__ eoff, const int* __restrict__ noff,
    int* __restrict__ epairs, unsigned short* __restrict__ nedges)
{
    const int bid = blockIdx.x;
    const int xcd = bid & 7;
    const int j   = bid >> 3;
    const int vb  = (xcd < SCAT_R) ? xcd * (SCAT_Q + 1) + j
                                   : SCAT_R * (SCAT_Q + 1) + (xcd - SCAT_R) * SCAT_Q + j;
    int i = vb * 256 + (int)threadIdx.x;
    if (i >= NNZ) return;
    int e = E[i], v = V[i];
    int be = i / CHUNK_E;
    int bn = i / CHUNK_N;
    int g  = i / 200000;            // = be/CPG_E = bn/CPG_N
    int pe = eoff[e] + gsum_e[(size_t)g * N_EDGES + e]
                     + part_e[(size_t)be * N_EDGES + e] + re[i];
    int pn = noff[v] + gsum_n[(size_t)g * N_NODES + v]
                     + part_n[(size_t)bn * N_NODES + v] + rn[i];
    epairs[pe] = v;
    nedges[pn] = (unsigned short)e;
}

// ---------------------------------------------------------------------------
// helper: accumulate 8 dims (8 halves packed in a float4) with weight w
// ---------------------------------------------------------------------------
__device__ __forceinline__ void acc8h(float w, float4 raw, float (&a)[8])
{
    const __half2* h = (const __half2*)&raw;
    #pragma unroll
    for (int t = 0; t < 4; ++t) {
        float2 f = __half22float2(h[t]);
        a[2*t]   = fmaf(w, f.x, a[2*t]);
        a[2*t+1] = fmaf(w, f.y, a[2*t+1]);
    }
}

// ---------------------------------------------------------------------------
// K8: per-edge aggregation. ONE WAVE PER EDGE, FOUR 16-LANE SLOTS.
// fp32 accumulation; fast elu epilogue.
// ---------------------------------------------------------------------------
__global__ __launch_bounds__(256) void k_edge_agg(
    const int* __restrict__ epairs, const int* __restrict__ eoff,
    const float* __restrict__ wexp,
    const __half* __restrict__ Xf16, const float* __restrict__ S,
    float* __restrict__ emsg)
{
    const int wave = threadIdx.x >> 6, lane = threadIdx.x & 63;
    const int e = blockIdx.x * 4 + wave;
    if (e >= N_EDGES) return;
    const int beg = eoff[e], end = eoff[e + 1];
    const int slot = lane >> 4;          // 0..3
    const int sl = lane & 15;            // dims 8*sl .. 8*sl+7
    float a[8] = {};
    float dsum = 0.f;
    int j = beg;
    #pragma unroll 2
    for (; j + 3 < end; j += 4) {
        int v = epairs[j + slot];
        float w = wexp[v];
        float4 r = *(const float4*)(Xf16 + (size_t)v * D + sl * 8);
        dsum += w;
        acc8h(w, r, a);
    }
    if (j + slot < end) {
        int v = epairs[j + slot];
        float w = wexp[v];
        float4 r = *(const float4*)(Xf16 + (size_t)v * D + sl * 8);
        dsum += w;
        acc8h(w, r, a);
    }
    #pragma unroll
    for (int k = 0; k < 8; ++k) {
        a[k] += __shfl_xor(a[k], 16, 64);
        a[k] += __shfl_xor(a[k], 32, 64);
    }
    dsum += __shfl_xor(dsum, 16, 64);
    dsum += __shfl_xor(dsum, 32, 64);

    float inv = (end > beg) ? 1.f / dsum : 0.f;
    float y[8];
    #pragma unroll
    for (int k = 0; k < 8; ++k)
        y[k] = elu_fast(a[k] * inv);
    const size_t rb = (size_t)e * (D + STAR);
    if (slot == 0) {
        *(float4*)(emsg + rb + sl * 8)     = make_float4(y[0], y[1], y[2], y[3]);
        *(float4*)(emsg + rb + sl * 8 + 4) = make_float4(y[4], y[5], y[6], y[7]);
    } else if (slot == 1) {
        float4 s4 = *(const float4*)(S + (size_t)e * STAR + sl * 4);
        *(float4*)(emsg + rb + D + sl * 4) = s4;
    }
}

// ---------------------------------------------------------------------------
// K9: edge GEMM on matrix cores: Y = e_msg @ Wt^T + Wt_b -> fp16.
// ---------------------------------------------------------------------------
__global__ __launch_bounds__(256) void k_edge_gemm(
    const float* __restrict__ A, const __half* __restrict__ Wtf16,
    const float* __restrict__ Wtb, __half* __restrict__ Y16)
{
    __shared__ char smem[64 * 384];   // 24 KB A-tile; head reused for repack
    const int KDIM = D + STAR;        // 192
    const int tid  = threadIdx.x;
    const int w    = tid >> 6;
    const int lane = tid & 63;
    const int bm   = blockIdx.x * 64;
    const int colbase = w * 32;       // 0,32,64,96
    const int r16 = lane & 15;
    const int hi  = lane >> 4;
    const int g8  = hi * 8;

    {
        const int r = tid >> 2;
        int srow = bm + r; if (srow >= N_EDGES) srow = N_EDGES - 1;
        const float4* src = (const float4*)(A + (size_t)srow * KDIM + (tid & 3) * 48);
        float4 f[12];
        #pragma unroll
        for (int j = 0; j < 12; ++j) f[j] = src[j];
        const int swz  = (r & 7) << 4;
        const int base = r * 384 + (tid & 3) * 96;
        #pragma unroll
        for (int j = 0; j < 6; ++j)
            *(half8*)(smem + ((base + j * 16) ^ swz)) = cvt8(f[2*j], f[2*j+1]);
    }

    half8 bf[6][2];
    #pragma unroll
    for (int ks = 0; ks < 6; ++ks)
        #pragma unroll
        for (int n = 0; n < 2; ++n)
            bf[ks][n] = *(const half8*)(Wtf16 + (size_t)(colbase + n*16 + r16) * KDIM
                                        + ks * 32 + g8);

    __syncthreads();

    floatx4 acc[4][2] = {};
    #pragma unroll
    for (int ks = 0; ks < 6; ++ks) {
        half8 a[4];
        #pragma unroll
        for (int m = 0; m < 4; ++m) {
            const int R = m * 16 + r16;
            a[m] = *(const half8*)(smem + ((R*384 + ks*64 + hi*16) ^ ((R&7)<<4)));
        }
        #pragma unroll
        for (int m = 0; m < 4; ++m)
            #pragma unroll
            for (int n = 0; n < 2; ++n)
                acc[m][n] = __builtin_amdgcn_mfma_f32_16x16x32_f16(
                    a[m], bf[ks][n], acc[m][n], 0, 0, 0);
    }

    const int rq = hi * 4;
    __syncthreads();   // A-tile dead

    {
        __half* sh = (__half*)smem;
        #pragma unroll
        for (int n = 0; n < 2; ++n) {
            const int c = colbase + n * 16 + r16;     // 0..127
            const float bv = Wtb[c];
            #pragma unroll
            for (int m = 0; m < 4; ++m)
                #pragma unroll
                for (int q = 0; q < 4; ++q)
                    sh[(m * 16 + rq + q) * 128 + c] =
                        __float2half(acc[m][n][q] + bv);
        }
    }
    __syncthreads();
    {
        const int r   = tid >> 2;
        const int row = bm + r;
        if (row < N_EDGES) {
            const char* src = smem + r * 256 + (tid & 3) * 64;
            __half* dst = Y16 + (size_t)row * D + (tid & 3) * 32;
            #pragma unroll
            for (int j = 0; j < 4; ++j)
                *(half8*)(dst + j * 8) = *(const half8*)(src + j * 16);
        }
    }
}

// ---------------------------------------------------------------------------
// K10: per-node aggregation. ONE WAVE PER NODE, FOUR 16-LANE SLOTS.
// fp32 accumulation (round-9 form; fp16 pk-accum regressed) + fast elu.
// out[v] = elu(mean_j Y[e_j]) + out[v]   (out holds X_init).
// ---------------------------------------------------------------------------
__global__ __launch_bounds__(256) void k_node_agg(
    const unsigned short* __restrict__ nedges, const int* __restrict__ noff,
    const __half* __restrict__ Y16, float* __restrict__ out)
{
    const int wave = threadIdx.x >> 6, lane = threadIdx.x & 63;
    const int v = blockIdx.x * 4 + wave;
    if (v >= N_NODES) return;
    const int beg = noff[v], end = noff[v + 1];
    const int slot = lane >> 4;
    const int sl = lane & 15;
    float a[8] = {};
    int j = beg;
    #pragma unroll 2
    for (; j + 3 < end; j += 4) {
        int e0 = nedges[j + slot];
        float4 r = *(const float4*)(Y16 + (size_t)e0 * D + sl * 8);
        acc8h(1.f, r, a);
    }
    if (j + slot < end) {
        int e0 = nedges[j + slot];
        float4 r = *(const float4*)(Y16 + (size_t)e0 * D + sl * 8);
        acc8h(1.f, r, a);
    }
    #pragma unroll
    for (int k = 0; k < 8; ++k) {
        a[k] += __shfl_xor(a[k], 16, 64);
        a[k] += __shfl_xor(a[k], 32, 64);
    }

    if (slot == 0) {
        int cnt = end - beg;
        float invc = 1.f / (float)max(cnt, 1);
        float x[8];
        #pragma unroll
        for (int k = 0; k < 8; ++k)
            x[k] = elu_fast(a[k] * invc);
        float4* o0 = (float4*)(out + (size_t)v * D + sl * 8);
        float4* o1 = (float4*)(out + (size_t)v * D + sl * 8 + 4);
        float4 c0 = *o0, c1 = *o1;
        *o0 = make_float4(c0.x + x[0], c0.y + x[1], c0.z + x[2], c0.w + x[3]);
        *o1 = make_float4(c1.x + x[4], c1.y + x[5], c1.z + x[6], c1.w + x[7]);
    }
}

// ---------------------------------------------------------------------------
extern "C" void kernel_launch(void* const* d_in, const int* in_sizes, int n_in,
                              void* d_out, int out_size, void* d_ws, size_t ws_size,
                              hipStream_t stream)
{
    const float* X    = (const float*)d_in[0];
    const int*   V    = (const int*)  d_in[1];
    const int*   E    = (const int*)  d_in[2];
    const float* S    = (const float*)d_in[3];
    const float* Wx_w = (const float*)d_in[4];
    const float* Wx_b = (const float*)d_in[5];
    const float* Wv_w = (const float*)d_in[6];
    const float* Wv_b = (const float*)d_in[7];
    const float* a_w  = (const float*)d_in[8];
    const float* Wt_w = (const float*)d_in[9];
    const float* Wt_b = (const float*)d_in[10];
    float* out = (float*)d_out;

    char* p = (char*)d_ws;
    auto take = [&](size_t bytes) -> char* {
        char* r = p;
        p += (bytes + 255) & ~(size_t)255;
        return r;
    };

    __half* Xf16  = (__half*)take((size_t)N_NODES * D * 2);
    float*  wexp  = (float*) take((size_t)N_NODES * 4);
    unsigned short* part_e = (unsigned short*)take((size_t)NBLK_E * N_EDGES * 2);
    unsigned short* part_n = (unsigned short*)take((size_t)NBLK_N * N_NODES * 2);
    int*    gsum_e = (int*)  take((size_t)NGRP * N_EDGES * 4);
    int*    gsum_n = (int*)  take((size_t)NGRP * N_NODES * 4);
    int*    tot_e = (int*)   take((size_t)N_EDGES * 4);
    int*    tot_n = (int*)   take((size_t)N_NODES * 4);
    int*    eoff  = (int*)   take((size_t)(N_EDGES + 1) * 4);
    int*    noff  = (int*)   take((size_t)(N_NODES + 1) * 4);
    int*    bsum_e = (int*)  take((size_t)SCB_E * 4);
    int*    bsum_n = (int*)  take((size_t)SCB_N * 4);
    unsigned short* re = (unsigned short*)take((size_t)NNZ * 2);
    unsigned short* rn = (unsigned short*)take((size_t)NNZ * 2);
    int*    epairs = (int*)  take((size_t)NNZ * 4);
    unsigned short* nedges = (unsigned short*)take((size_t)NNZ * 2);
    float*  emsg  = (float*) take((size_t)N_EDGES * (D + STAR) * 4);
    __half* Y16   = (__half*)take((size_t)N_EDGES * D * 2);
    __half* Wf16  = (__half*)take((size_t)256 * D * 2);          // [Wx;Wv] fp16
    __half* Wtf16 = (__half*)take((size_t)D * (D + STAR) * 2);   // Wt fp16

    k_cvt_w<<<56, 256, 0, stream>>>(Wx_w, Wv_w, Wt_w, Wf16, Wtf16);

    k_node_gemm<<<(N_NODES + 63) / 64, 256, 0, stream>>>(
        X, Wf16, Wx_b, Wv_b, a_w, out, Xf16, wexp);

    k_part_all<<<NBLK_E + NBLK_N * NPASS_N, 256, 0, stream>>>(
        E, V, part_e, part_n, re, rn);

    // merged two-level chunk scans + offset scans (5 launches)
    k_tot_grp2<<<dim3(TGB_E + TGB_N, NGRP), 256, 0, stream>>>(
        part_e, gsum_e, part_n, gsum_n);
    k_tot_fin2<<<TGB_E + TGB_N, 256, 0, stream>>>(
        gsum_e, tot_e, gsum_n, tot_n);
    k_scan_bsum2<<<SCB_E + SCB_N, 256, 0, stream>>>(
        tot_e, bsum_e, tot_n, bsum_n);
    k_scan_bbase2<<<2, 1024, 0, stream>>>(bsum_e, eoff, bsum_n, noff);
    k_scan_out2<<<SCB_E + SCB_N, 256, 0, stream>>>(
        tot_e, bsum_e, eoff, tot_n, bsum_n, noff);

    k_scatter_both<<<SCAT_NWG, 256, 0, stream>>>(
        V, E, re, rn, part_e, part_n, gsum_e, gsum_n,
        eoff, noff, epairs, nedges);

    k_edge_agg<<<(N_EDGES + 3) / 4, 256, 0, stream>>>(
        epairs, eoff, wexp, Xf16, S, emsg);

    k_edge_gemm<<<(N_EDGES + 63) / 64, 256, 0, stream>>>(emsg, Wtf16, Wt_b, Y16);

    k_node_agg<<<(N_NODES + 3) / 4, 256, 0, stream>>>(nedges, noff, Y16, out);
}

// Round 13
// 383.595 us; speedup vs baseline: 1.1346x; 1.0416x over previous
//
#include <hip/hip_runtime.h>
#include <hip/hip_bf16.h>
#include <hip/hip_fp16.h>

#define N_NODES 100000
#define N_EDGES 20000
#define NNZ     1600000
#define D       128
#define STAR    64
#define NEG_SLOPE 0.2f

// edge counting-sort: SINGLE pass, 20000 bins packed as 2xushort per int (40 KB).
#define NBLK_E  400
#define CHUNK_E 4000        // NNZ / NBLK_E
#define H32_E   10000       // ints = 20000 packed ushort bins

// node counting-sort: 5 passes of 20000 packed-ushort bins (40 KB LDS).
#define NBLK_N  64
#define CHUNK_N 25000       // NNZ / NBLK_N
#define BINS_N  20000
#define H32_N   10000
#define NPASS_N 5

// two-level chunk scan: 8 groups for both partitions (== 8 XCDs)
#define NGRP    8
#define CPG_E   (NBLK_E / NGRP)   // 50 chunks per group
#define CPG_N   (NBLK_N / NGRP)   // 8 chunks per group

// scatter grid geometry for XCD-chunked remap
#define SCAT_NWG ((NNZ + 255) / 256)   // 6250
#define SCAT_Q   (SCAT_NWG / 8)        // 781
#define SCAT_R   (SCAT_NWG % 8)        // 2

// merged scan-pipeline grids
#define TGB_E ((N_EDGES + 255) / 256)   // 79  bin-blocks (edge)
#define TGB_N ((N_NODES + 255) / 256)   // 391 bin-blocks (node)

// multi-block scan: 256 threads x 16 elements
#define SCC 16
#define SC_PER_BLOCK (256 * SCC)   // 4096
#define SCB_E ((N_EDGES + SC_PER_BLOCK - 1) / SC_PER_BLOCK)   // 5
#define SCB_N ((N_NODES + SC_PER_BLOCK - 1) / SC_PER_BLOCK)   // 25

typedef _Float16 half8 __attribute__((ext_vector_type(8)));
typedef float    floatx4 __attribute__((ext_vector_type(4)));

// fast elu: expm1 via v_exp (abs err ~1e-7, fine at 1.6e-2 tolerance)
__device__ __forceinline__ float elu_fast(float t)
{
    return (t > 0.f) ? t : (__expf(t) - 1.f);
}

// pack 8 fp32 (two float4) -> half8 fragment
__device__ __forceinline__ half8 cvt8(float4 f0, float4 f1)
{
    half8 h;
    h[0] = (_Float16)f0.x; h[1] = (_Float16)f0.y;
    h[2] = (_Float16)f0.z; h[3] = (_Float16)f0.w;
    h[4] = (_Float16)f1.x; h[5] = (_Float16)f1.y;
    h[6] = (_Float16)f1.z; h[7] = (_Float16)f1.w;
    return h;
}

// ---------------------------------------------------------------------------
// K0: one-time fp32 -> fp16 weight conversion.
// ---------------------------------------------------------------------------
__global__ __launch_bounds__(256) void k_cvt_w(
    const float* __restrict__ Wx, const float* __restrict__ Wv,
    const float* __restrict__ Wt,
    __half* __restrict__ Wf16, __half* __restrict__ Wtf16)
{
    int i = (blockIdx.x * 256 + threadIdx.x) * 4;
    const float* src;
    __half* dst;
    if (i < 16384)            { src = Wx + i;         dst = Wf16 + i; }
    else if (i < 32768)       { src = Wv + (i-16384); dst = Wf16 + i; }
    else if (i < 32768+24576) { src = Wt + (i-32768); dst = Wtf16 + (i-32768); }
    else return;
    float4 f = *(const float4*)src;
    *(__half2*)(dst)     = __floats2half2_rn(f.x, f.y);
    *(__half2*)(dst + 2) = __floats2half2_rn(f.z, f.w);
}

// ---------------------------------------------------------------------------
// K1: fused node GEMM on matrix cores + FUSED SCORE, SWAPPED-OPERAND MFMA.
//   [X_init | X_feat] = X @ [Wx^T | Wv^T] + bias;  wexp = exp(lrelu(Xf.a))
// mfma(bf, af) computes C^T: lane (r16,hi) holds, for frag (m,n),
// node row = bm+m*16+r16 and 4 CONSECUTIVE cols colbase+n*16+hi*4+q.
// -> fp32 X_init epilogue = 16 float4 stores/thread (was 64 scalar);
// -> fp16 repack = 8-B LDS stores, XOR-swizzled ((row&7)<<4) vs the
//    256-B-row-stride bank conflict (round-11: 1.3M conflicts).
// ---------------------------------------------------------------------------
__global__ __launch_bounds__(256) void k_node_gemm(
    const float* __restrict__ X, const __half* __restrict__ Wf16,
    const float* __restrict__ Wxb, const float* __restrict__ Wvb,
    const float* __restrict__ aw,
    float* __restrict__ Xinit, __half* __restrict__ Xf16,
    float* __restrict__ wexp)
{
    __shared__ char smem[64 * 256];   // 16 KB A-tile; reused for fp16 repack
    const int tid  = threadIdx.x;
    const int w    = tid >> 6;
    const int lane = tid & 63;
    const int bm   = blockIdx.x * 64;
    const int colbase = w * 64;               // 0,64,128,192
    const bool isInit = (colbase < D);
    const int r16 = lane & 15;
    const int hi  = lane >> 4;                // 0..3
    const int g8  = hi * 8;

    // ---- stage A tile: coalesced fp32 load -> fp16 -> swizzled LDS ----
    {
        const int r  = tid >> 2;              // 0..63
        int srow = bm + r; if (srow >= N_NODES) srow = N_NODES - 1;
        const float4* src = (const float4*)(X + (size_t)srow * D + (tid & 3) * 32);
        float4 f[8];
        #pragma unroll
        for (int j = 0; j < 8; ++j) f[j] = src[j];
        const int swz  = (r & 7) << 4;
        const int base = r * 256 + (tid & 3) * 64;
        #pragma unroll
        for (int j = 0; j < 4; ++j)
            *(half8*)(smem + ((base + j * 16) ^ swz)) = cvt8(f[2*j], f[2*j+1]);
    }

    // ---- hoist all 16 B fragments (fp16, L2-resident) ----
    half8 bf[4][4];
    #pragma unroll
    for (int ks = 0; ks < 4; ++ks)
        #pragma unroll
        for (int n = 0; n < 4; ++n)
            bf[ks][n] = *(const half8*)(Wf16 + (size_t)(colbase + n*16 + r16) * D
                                        + ks * 32 + g8);

    __syncthreads();

    floatx4 acc[4][4] = {};
    #pragma unroll
    for (int ks = 0; ks < 4; ++ks) {
        half8 a[4];
        #pragma unroll
        for (int m = 0; m < 4; ++m) {
            const int R = m * 16 + r16;
            a[m] = *(const half8*)(smem + ((R*256 + ks*64 + hi*16) ^ ((R&7)<<4)));
        }
        // SWAPPED operands: compute C^T so each lane owns 4 consecutive cols
        #pragma unroll
        for (int m = 0; m < 4; ++m)
            #pragma unroll
            for (int n = 0; n < 4; ++n)
                acc[m][n] = __builtin_amdgcn_mfma_f32_16x16x32_f16(
                    bf[ks][n], a[m], acc[m][n], 0, 0, 0);
    }

    const float* bias = isInit ? Wxb : Wvb;

    __syncthreads();   // A-tile dead; smem reusable

    if (isInit) {
        // float4 stores: lane owns row bm+m*16+r16, cols c4..c4+3
        #pragma unroll
        for (int n = 0; n < 4; ++n) {
            const int c4 = (colbase & (D - 1)) + n * 16 + hi * 4;
            float4 bb = *(const float4*)(bias + c4);
            #pragma unroll
            for (int m = 0; m < 4; ++m) {
                const int row = bm + m * 16 + r16;
                if (row < N_NODES) {
                    float4 o = make_float4(acc[m][n][0] + bb.x, acc[m][n][1] + bb.y,
                                           acc[m][n][2] + bb.z, acc[m][n][3] + bb.w);
                    *(float4*)(Xinit + (size_t)row * D + c4) = o;
                }
            }
        }
    } else {
        // scatter fp16 (8-B chunks) into XOR-swizzled LDS tile [64][128]
        #pragma unroll
        for (int n = 0; n < 4; ++n) {
            const int c4 = (colbase & (D - 1)) + n * 16 + hi * 4;
            float4 bb = *(const float4*)(bias + c4);
            const int lcb = ((colbase - D) + n * 16 + hi * 4) * 2;   // byte col
            #pragma unroll
            for (int m = 0; m < 4; ++m) {
                const int row = m * 16 + r16;
                char* dst = smem + row * 256 + (lcb ^ ((row & 7) << 4));
                *(__half2*)(dst)     = __floats2half2_rn(acc[m][n][0] + bb.x,
                                                         acc[m][n][1] + bb.y);
                *(__half2*)(dst + 4) = __floats2half2_rn(acc[m][n][2] + bb.z,
                                                         acc[m][n][3] + bb.w);
            }
        }
    }
    __syncthreads();
    // coalesced Xf16 store + fused score (4 threads per row), un-swizzled read
    {
        const int r   = tid >> 2;
        const int row = bm + r;
        const int q4  = tid & 3;
        if (row < N_NODES) {
            const int swz = (r & 7) << 4;
            __half* dst = Xf16 + (size_t)row * D + q4 * 32;
            float part = 0.f;
            #pragma unroll
            for (int j = 0; j < 4; ++j) {
                half8 h = *(const half8*)(smem + r * 256 + ((q4 * 64 + j * 16) ^ swz));
                *(half8*)(dst + j * 8) = h;
                float4 a0 = *(const float4*)(aw + q4 * 32 + j * 8);
                float4 a1 = *(const float4*)(aw + q4 * 32 + j * 8 + 4);
                part += (float)h[0]*a0.x + (float)h[1]*a0.y
                      + (float)h[2]*a0.z + (float)h[3]*a0.w
                      + (float)h[4]*a1.x + (float)h[5]*a1.y
                      + (float)h[6]*a1.z + (float)h[7]*a1.w;
            }
            part += __shfl_xor(part, 1, 64);
            part += __shfl_xor(part, 2, 64);
            if (q4 == 0) {
                float l = (part > 0.f) ? part : NEG_SLOPE * part;
                wexp[row] = expf(l);
            }
        }
    }
}

// ---------------------------------------------------------------------------
// K3: MERGED histogram+rank kernel (edge single-pass + node 5-pass),
// 40 KB packed-ushort LDS bins, rank = halfword of LDS atomicAdd return.
// ---------------------------------------------------------------------------
__global__ __launch_bounds__(256) void k_part_all(
    const int* __restrict__ E, const int* __restrict__ V,
    unsigned short* __restrict__ part_e, unsigned short* __restrict__ part_n,
    unsigned short* __restrict__ re, unsigned short* __restrict__ rn)
{
    __shared__ int h[H32_E];   // 10000 ints = 40 KB (H32_E == H32_N)
    const int blk = blockIdx.x;
    for (int t = threadIdx.x; t < H32_E; t += 256) h[t] = 0;
    __syncthreads();

    if (blk < NBLK_E) {
        const int b = blk;
        const int i0 = b * CHUNK_E;
        const int4* E4 = (const int4*)(E + i0);
        for (int i = threadIdx.x; i < CHUNK_E / 4; i += 256) {
            int4 q = E4[i];
            int ev[4] = {q.x, q.y, q.z, q.w};
            #pragma unroll
            for (int t = 0; t < 4; ++t) {
                int e = ev[t];
                unsigned sh = (e & 1) << 4;
                int old = atomicAdd(&h[e >> 1], 1 << sh);
                re[i0 + i * 4 + t] = (unsigned short)((unsigned)old >> sh);
            }
        }
        __syncthreads();
        int* dst = (int*)(part_e + (size_t)b * N_EDGES);
        for (int t = threadIdx.x; t < H32_E; t += 256) dst[t] = h[t];
    } else {
        const int idx = blk - NBLK_E;        // 0..319
        const int b   = idx & 63;            // node chunk
        const int c0  = (idx >> 6) * BINS_N; // pass * 20000
        const int i0  = b * CHUNK_N;
        const int4* V4 = (const int4*)(V + i0);
        for (int i = threadIdx.x; i < CHUNK_N / 4; i += 256) {
            int4 q = V4[i];
            int vv[4] = {q.x, q.y, q.z, q.w};
            #pragma unroll
            for (int t = 0; t < 4; ++t) {
                int c = vv[t] - c0;
                if ((unsigned)c < (unsigned)BINS_N) {
                    unsigned sh = (c & 1) << 4;
                    int old = atomicAdd(&h[c >> 1], 1 << sh);
                    rn[i0 + i * 4 + t] = (unsigned short)((unsigned)old >> sh);
                }
            }
        }
        __syncthreads();
        int* dst = (int*)(part_n + (size_t)b * N_NODES + c0);
        for (int t = threadIdx.x; t < H32_N; t += 256) dst[t] = h[t];
    }
}

// ---------------------------------------------------------------------------
// K5a: MERGED within-group scan (edge blocks [0,79), node [79,470)).
// ---------------------------------------------------------------------------
__global__ __launch_bounds__(256) void k_tot_grp2(
    unsigned short* __restrict__ part_e, int* __restrict__ gsum_e,
    unsigned short* __restrict__ part_n, int* __restrict__ gsum_n)
{
    const int g = blockIdx.y;
    unsigned short* part; int* gsum; int nbins, cpg, bin;
    if (blockIdx.x < TGB_E) {
        bin = blockIdx.x * 256 + threadIdx.x;
        part = part_e; gsum = gsum_e; nbins = N_EDGES; cpg = CPG_E;
    } else {
        bin = (blockIdx.x - TGB_E) * 256 + threadIdx.x;
        part = part_n; gsum = gsum_n; nbins = N_NODES; cpg = CPG_N;
    }
    if (bin >= nbins) return;
    int run = 0;
    #pragma unroll 8
    for (int b = g * cpg; b < (g + 1) * cpg; ++b) {
        size_t idx = (size_t)b * nbins + bin;
        int v = part[idx];
        part[idx] = (unsigned short)run;
        run += v;
    }
    gsum[(size_t)g * nbins + bin] = run;
}

// ---------------------------------------------------------------------------
// K5b: MERGED exclusive scan over the NGRP group sums; emits tot.
// ---------------------------------------------------------------------------
__global__ __launch_bounds__(256) void k_tot_fin2(
    int* __restrict__ gsum_e, int* __restrict__ tot_e,
    int* __restrict__ gsum_n, int* __restrict__ tot_n)
{
    int* gsum; int* tot; int nbins, bin;
    if (blockIdx.x < TGB_E) {
        bin = blockIdx.x * 256 + threadIdx.x;
        gsum = gsum_e; tot = tot_e; nbins = N_EDGES;
    } else {
        bin = (blockIdx.x - TGB_E) * 256 + threadIdx.x;
        gsum = gsum_n; tot = tot_n; nbins = N_NODES;
    }
    if (bin >= nbins) return;
    int run = 0;
    #pragma unroll
    for (int g = 0; g < NGRP; ++g) {
        size_t idx = (size_t)g * nbins + bin;
        int v = gsum[idx];
        gsum[idx] = run;
        run += v;
    }
    tot[bin] = run;
}

// ---------------------------------------------------------------------------
// MERGED multi-block scan phase 1: edge blocks [0,5), node [5,30).
// ---------------------------------------------------------------------------
__global__ __launch_bounds__(256) void k_scan_bsum2(
    const int* __restrict__ tot_e, int* __restrict__ bsum_e,
    const int* __restrict__ tot_n, int* __restrict__ bsum_n)
{
    __shared__ int red[256];
    const int* cnt; int* bsum; int n, blk;
    if (blockIdx.x < SCB_E) { cnt = tot_e; bsum = bsum_e; n = N_EDGES; blk = blockIdx.x; }
    else { cnt = tot_n; bsum = bsum_n; n = N_NODES; blk = blockIdx.x - SCB_E; }
    const int base = blk * SC_PER_BLOCK + threadIdx.x * SCC;
    int s = 0;
    if (base + SCC <= n) {
        const int4* p4 = (const int4*)(cnt + base);
        #pragma unroll
        for (int j = 0; j < SCC / 4; ++j) {
            int4 v = p4[j];
            s += v.x + v.y + v.z + v.w;
        }
    } else {
        for (int i = base; i < n; ++i) s += cnt[i];
    }
    red[threadIdx.x] = s;
    __syncthreads();
    for (int d = 128; d > 0; d >>= 1) {
        if (threadIdx.x < d) red[threadIdx.x] += red[threadIdx.x + d];
        __syncthreads();
    }
    if (threadIdx.x == 0) bsum[blk] = red[0];
}

// ---------------------------------------------------------------------------
// MERGED phase 2 (block 0 = edge, block 1 = node): exclusive block bases,
// writes total into off[n].
// ---------------------------------------------------------------------------
__global__ __launch_bounds__(1024) void k_scan_bbase2(
    int* __restrict__ bsum_e, int* __restrict__ eoff,
    int* __restrict__ bsum_n, int* __restrict__ noff)
{
    __shared__ int sums[1024];
    int* bsum; int* off; int nb, n;
    if (blockIdx.x == 0) { bsum = bsum_e; off = eoff; nb = SCB_E; n = N_EDGES; }
    else                 { bsum = bsum_n; off = noff; nb = SCB_N; n = N_NODES; }
    const int tid = threadIdx.x;
    sums[tid] = (tid < nb) ? bsum[tid] : 0;
    __syncthreads();
    for (int d = 1; d < 1024; d <<= 1) {
        int mine = sums[tid];
        int other = (tid >= d) ? sums[tid - d] : 0;
        __syncthreads();
        sums[tid] = mine + other;
        __syncthreads();
    }
    if (tid < nb) bsum[tid] = (tid > 0) ? sums[tid - 1] : 0;
    if (tid == 0) off[n] = sums[1023];
}

// ---------------------------------------------------------------------------
// MERGED phase 3: per-block exclusive scan + block base -> off[i].
// ---------------------------------------------------------------------------
__global__ __launch_bounds__(256) void k_scan_out2(
    const int* __restrict__ tot_e, const int* __restrict__ bsum_e,
    int* __restrict__ eoff,
    const int* __restrict__ tot_n, const int* __restrict__ bsum_n,
    int* __restrict__ noff)
{
    __shared__ int tsum[256];
    const int* cnt; const int* bsum; int* off; int n, blk;
    if (blockIdx.x < SCB_E) {
        cnt = tot_e; bsum = bsum_e; off = eoff; n = N_EDGES; blk = blockIdx.x;
    } else {
        cnt = tot_n; bsum = bsum_n; off = noff; n = N_NODES; blk = blockIdx.x - SCB_E;
    }
    const int base = blk * SC_PER_BLOCK + threadIdx.x * SCC;
    int vals[SCC];
    int s = 0;
    if (base + SCC <= n) {
        const int4* p4 = (const int4*)(cnt + base);
        #pragma unroll
        for (int j = 0; j < SCC / 4; ++j) {
            int4 v = p4[j];
            vals[4 * j + 0] = v.x; vals[4 * j + 1] = v.y;
            vals[4 * j + 2] = v.z; vals[4 * j + 3] = v.w;
            s += v.x + v.y + v.z + v.w;
        }
    } else {
        #pragma unroll
        for (int j = 0; j < SCC; ++j) {
            int i = base + j;
            vals[j] = (i < n) ? cnt[i] : 0;
            s += vals[j];
        }
    }
    tsum[threadIdx.x] = s;
    __syncthreads();
    for (int d = 1; d < 256; d <<= 1) {
        int mine = tsum[threadIdx.x];
        int other = (threadIdx.x >= d) ? tsum[threadIdx.x - d] : 0;
        __syncthreads();
        tsum[threadIdx.x] = mine + other;
        __syncthreads();
    }
    int run = bsum[blk] + ((threadIdx.x > 0) ? tsum[threadIdx.x - 1] : 0);
    #pragma unroll
    for (int j = 0; j < SCC; ++j) {
        int i = base + j;
        if (i < n) { off[i] = run; run += vals[j]; }
    }
}

// ---------------------------------------------------------------------------
// K6: FUSED flat scatter, XCD-CHUNKED (bid%8 == presumed XCD processes the
// matching contiguous group of incidences so each output line is written
// by ~1 XCD). Correctness is mapping-independent (pure bijection on i).
// ---------------------------------------------------------------------------
__global__ __launch_bounds__(256) void k_scatter_both(
    const int* __restrict__ V, const int* __restrict__ E,
    const unsigned short* __restrict__ re, const unsigned short* __restrict__ rn,
    const unsigned short* __restrict__ part_e,
    const unsigned short* __restrict__ part_n,
    const int* __restrict__ gsum_e, const int* __restrict__ gsum_n,
    const int* __restrict__ eoff, const int* __restrict__ noff,
    int* __restrict__ epairs, unsigned short* __restrict__ nedges)
{
    const int bid = blockIdx.x;
    const int xcd = bid & 7;
    const int j   = bid >> 3;
    const int vb  = (xcd < SCAT_R) ? xcd * (SCAT_Q + 1) + j
                                   : SCAT_R * (SCAT_Q + 1) + (xcd - SCAT_R) * SCAT_Q + j;
    int i = vb * 256 + (int)threadIdx.x;
    if (i >= NNZ) return;
    int e = E[i], v = V[i];
    int be = i / CHUNK_E;
    int bn = i / CHUNK_N;
    int g  = i / 200000;            // = be/CPG_E = bn/CPG_N
    int pe = eoff[e] + gsum_e[(size_t)g * N_EDGES + e]
                     + part_e[(size_t)be * N_EDGES + e] + re[i];
    int pn = noff[v] + gsum_n[(size_t)g * N_NODES + v]
                     + part_n[(size_t)bn * N_NODES + v] + rn[i];
    epairs[pe] = v;
    nedges[pn] = (unsigned short)e;
}

// ---------------------------------------------------------------------------
// helper: accumulate 8 dims (8 halves packed in a float4) with weight w
// ---------------------------------------------------------------------------
__device__ __forceinline__ void acc8h(float w, float4 raw, float (&a)[8])
{
    const __half2* h = (const __half2*)&raw;
    #pragma unroll
    for (int t = 0; t < 4; ++t) {
        float2 f = __half22float2(h[t]);
        a[2*t]   = fmaf(w, f.x, a[2*t]);
        a[2*t+1] = fmaf(w, f.y, a[2*t+1]);
    }
}

// ---------------------------------------------------------------------------
// K8: per-edge aggregation. ONE WAVE PER EDGE, FOUR 16-LANE SLOTS.
// fp32 accumulation; fast elu epilogue.
// ---------------------------------------------------------------------------
__global__ __launch_bounds__(256) void k_edge_agg(
    const int* __restrict__ epairs, const int* __restrict__ eoff,
    const float* __restrict__ wexp,
    const __half* __restrict__ Xf16, const float* __restrict__ S,
    float* __restrict__ emsg)
{
    const int wave = threadIdx.x >> 6, lane = threadIdx.x & 63;
    const int e = blockIdx.x * 4 + wave;
    if (e >= N_EDGES) return;
    const int beg = eoff[e], end = eoff[e + 1];
    const int slot = lane >> 4;          // 0..3
    const int sl = lane & 15;            // dims 8*sl .. 8*sl+7
    float a[8] = {};
    float dsum = 0.f;
    int j = beg;
    #pragma unroll 2
    for (; j + 3 < end; j += 4) {
        int v = epairs[j + slot];
        float w = wexp[v];
        float4 r = *(const float4*)(Xf16 + (size_t)v * D + sl * 8);
        dsum += w;
        acc8h(w, r, a);
    }
    if (j + slot < end) {
        int v = epairs[j + slot];
        float w = wexp[v];
        float4 r = *(const float4*)(Xf16 + (size_t)v * D + sl * 8);
        dsum += w;
        acc8h(w, r, a);
    }
    #pragma unroll
    for (int k = 0; k < 8; ++k) {
        a[k] += __shfl_xor(a[k], 16, 64);
        a[k] += __shfl_xor(a[k], 32, 64);
    }
    dsum += __shfl_xor(dsum, 16, 64);
    dsum += __shfl_xor(dsum, 32, 64);

    float inv = (end > beg) ? 1.f / dsum : 0.f;
    float y[8];
    #pragma unroll
    for (int k = 0; k < 8; ++k)
        y[k] = elu_fast(a[k] * inv);
    const size_t rb = (size_t)e * (D + STAR);
    if (slot == 0) {
        *(float4*)(emsg + rb + sl * 8)     = make_float4(y[0], y[1], y[2], y[3]);
        *(float4*)(emsg + rb + sl * 8 + 4) = make_float4(y[4], y[5], y[6], y[7]);
    } else if (slot == 1) {
        float4 s4 = *(const float4*)(S + (size_t)e * STAR + sl * 4);
        *(float4*)(emsg + rb + D + sl * 4) = s4;
    }
}

// ---------------------------------------------------------------------------
// K9: edge GEMM on matrix cores: Y = e_msg @ Wt^T + Wt_b -> fp16.
// ---------------------------------------------------------------------------
__global__ __launch_bounds__(256) void k_edge_gemm(
    const float* __restrict__ A, const __half* __restrict__ Wtf16,
    const float* __restrict__ Wtb, __half* __restrict__ Y16)
{
    __shared__ char smem[64 * 384];   // 24 KB A-tile; head reused for repack
    const int KDIM = D + STAR;        // 192
    const int tid  = threadIdx.x;
    const int w    = tid >> 6;
    const int lane = tid & 63;
    const int bm   = blockIdx.x * 64;
    const int colbase = w * 32;       // 0,32,64,96
    const int r16 = lane & 15;
    const int hi  = lane >> 4;
    const int g8  = hi * 8;

    {
        const int r = tid >> 2;
        int srow = bm + r; if (srow >= N_EDGES) srow = N_EDGES - 1;
        const float4* src = (const float4*)(A + (size_t)srow * KDIM + (tid & 3) * 48);
        float4 f[12];
        #pragma unroll
        for (int j = 0; j < 12; ++j) f[j] = src[j];
        const int swz  = (r & 7) << 4;
        const int base = r * 384 + (tid & 3) * 96;
        #pragma unroll
        for (int j = 0; j < 6; ++j)
            *(half8*)(smem + ((base + j * 16) ^ swz)) = cvt8(f[2*j], f[2*j+1]);
    }

    half8 bf[6][2];
    #pragma unroll
    for (int ks = 0; ks < 6; ++ks)
        #pragma unroll
        for (int n = 0; n < 2; ++n)
            bf[ks][n] = *(const half8*)(Wtf16 + (size_t)(colbase + n*16 + r16) * KDIM
                                        + ks * 32 + g8);

    __syncthreads();

    floatx4 acc[4][2] = {};
    #pragma unroll
    for (int ks = 0; ks < 6; ++ks) {
        half8 a[4];
        #pragma unroll
        for (int m = 0; m < 4; ++m) {
            const int R = m * 16 + r16;
            a[m] = *(const half8*)(smem + ((R*384 + ks*64 + hi*16) ^ ((R&7)<<4)));
        }
        #pragma unroll
        for (int m = 0; m < 4; ++m)
            #pragma unroll
            for (int n = 0; n < 2; ++n)
                acc[m][n] = __builtin_amdgcn_mfma_f32_16x16x32_f16(
                    a[m], bf[ks][n], acc[m][n], 0, 0, 0);
    }

    const int rq = hi * 4;
    __syncthreads();   // A-tile dead

    {
        __half* sh = (__half*)smem;
        #pragma unroll
        for (int n = 0; n < 2; ++n) {
            const int c = colbase + n * 16 + r16;     // 0..127
            const float bv = Wtb[c];
            #pragma unroll
            for (int m = 0; m < 4; ++m)
                #pragma unroll
                for (int q = 0; q < 4; ++q)
                    sh[(m * 16 + rq + q) * 128 + c] =
                        __float2half(acc[m][n][q] + bv);
        }
    }
    __syncthreads();
    {
        const int r   = tid >> 2;
        const int row = bm + r;
        if (row < N_EDGES) {
            const char* src = smem + r * 256 + (tid & 3) * 64;
            __half* dst = Y16 + (size_t)row * D + (tid & 3) * 32;
            #pragma unroll
            for (int j = 0; j < 4; ++j)
                *(half8*)(dst + j * 8) = *(const half8*)(src + j * 16);
        }
    }
}

// ---------------------------------------------------------------------------
// K10: per-node aggregation. ONE WAVE PER NODE, FOUR 16-LANE SLOTS.
// fp32 accumulation + fast elu.
// out[v] = elu(mean_j Y[e_j]) + out[v]   (out holds X_init).
// ---------------------------------------------------------------------------
__global__ __launch_bounds__(256) void k_node_agg(
    const unsigned short* __restrict__ nedges, const int* __restrict__ noff,
    const __half* __restrict__ Y16, float* __restrict__ out)
{
    const int wave = threadIdx.x >> 6, lane = threadIdx.x & 63;
    const int v = blockIdx.x * 4 + wave;
    if (v >= N_NODES) return;
    const int beg = noff[v], end = noff[v + 1];
    const int slot = lane >> 4;
    const int sl = lane & 15;
    float a[8] = {};
    int j = beg;
    #pragma unroll 2
    for (; j + 3 < end; j += 4) {
        int e0 = nedges[j + slot];
        float4 r = *(const float4*)(Y16 + (size_t)e0 * D + sl * 8);
        acc8h(1.f, r, a);
    }
    if (j + slot < end) {
        int e0 = nedges[j + slot];
        float4 r = *(const float4*)(Y16 + (size_t)e0 * D + sl * 8);
        acc8h(1.f, r, a);
    }
    #pragma unroll
    for (int k = 0; k < 8; ++k) {
        a[k] += __shfl_xor(a[k], 16, 64);
        a[k] += __shfl_xor(a[k], 32, 64);
    }

    if (slot == 0) {
        int cnt = end - beg;
        float invc = 1.f / (float)max(cnt, 1);
        float x[8];
        #pragma unroll
        for (int k = 0; k < 8; ++k)
            x[k] = elu_fast(a[k] * invc);
        float4* o0 = (float4*)(out + (size_t)v * D + sl * 8);
        float4* o1 = (float4*)(out + (size_t)v * D + sl * 8 + 4);
        float4 c0 = *o0, c1 = *o1;
        *o0 = make_float4(c0.x + x[0], c0.y + x[1], c0.z + x[2], c0.w + x[3]);
        *o1 = make_float4(c1.x + x[4], c1.y + x[5], c1.z + x[6], c1.w + x[7]);
    }
}

// ---------------------------------------------------------------------------
extern "C" void kernel_launch(void* const* d_in, const int* in_sizes, int n_in,
                              void* d_out, int out_size, void* d_ws, size_t ws_size,
                              hipStream_t stream)
{
    const float* X    = (const float*)d_in[0];
    const int*   V    = (const int*)  d_in[1];
    const int*   E    = (const int*)  d_in[2];
    const float* S    = (const float*)d_in[3];
    const float* Wx_w = (const float*)d_in[4];
    const float* Wx_b = (const float*)d_in[5];
    const float* Wv_w = (const float*)d_in[6];
    const float* Wv_b = (const float*)d_in[7];
    const float* a_w  = (const float*)d_in[8];
    const float* Wt_w = (const float*)d_in[9];
    const float* Wt_b = (const float*)d_in[10];
    float* out = (float*)d_out;

    char* p = (char*)d_ws;
    auto take = [&](size_t bytes) -> char* {
        char* r = p;
        p += (bytes + 255) & ~(size_t)255;
        return r;
    };

    __half* Xf16  = (__half*)take((size_t)N_NODES * D * 2);
    float*  wexp  = (float*) take((size_t)N_NODES * 4);
    unsigned short* part_e = (unsigned short*)take((size_t)NBLK_E * N_EDGES * 2);
    unsigned short* part_n = (unsigned short*)take((size_t)NBLK_N * N_NODES * 2);
    int*    gsum_e = (int*)  take((size_t)NGRP * N_EDGES * 4);
    int*    gsum_n = (int*)  take((size_t)NGRP * N_NODES * 4);
    int*    tot_e = (int*)   take((size_t)N_EDGES * 4);
    int*    tot_n = (int*)   take((size_t)N_NODES * 4);
    int*    eoff  = (int*)   take((size_t)(N_EDGES + 1) * 4);
    int*    noff  = (int*)   take((size_t)(N_NODES + 1) * 4);
    int*    bsum_e = (int*)  take((size_t)SCB_E * 4);
    int*    bsum_n = (int*)  take((size_t)SCB_N * 4);
    unsigned short* re = (unsigned short*)take((size_t)NNZ * 2);
    unsigned short* rn = (unsigned short*)take((size_t)NNZ * 2);
    int*    epairs = (int*)  take((size_t)NNZ * 4);
    unsigned short* nedges = (unsigned short*)take((size_t)NNZ * 2);
    float*  emsg  = (float*) take((size_t)N_EDGES * (D + STAR) * 4);
    __half* Y16   = (__half*)take((size_t)N_EDGES * D * 2);
    __half* Wf16  = (__half*)take((size_t)256 * D * 2);          // [Wx;Wv] fp16
    __half* Wtf16 = (__half*)take((size_t)D * (D + STAR) * 2);   // Wt fp16

    k_cvt_w<<<56, 256, 0, stream>>>(Wx_w, Wv_w, Wt_w, Wf16, Wtf16);

    k_node_gemm<<<(N_NODES + 63) / 64, 256, 0, stream>>>(
        X, Wf16, Wx_b, Wv_b, a_w, out, Xf16, wexp);

    k_part_all<<<NBLK_E + NBLK_N * NPASS_N, 256, 0, stream>>>(
        E, V, part_e, part_n, re, rn);

    // merged two-level chunk scans + offset scans (5 launches)
    k_tot_grp2<<<dim3(TGB_E + TGB_N, NGRP), 256, 0, stream>>>(
        part_e, gsum_e, part_n, gsum_n);
    k_tot_fin2<<<TGB_E + TGB_N, 256, 0, stream>>>(
        gsum_e, tot_e, gsum_n, tot_n);
    k_scan_bsum2<<<SCB_E + SCB_N, 256, 0, stream>>>(
        tot_e, bsum_e, tot_n, bsum_n);
    k_scan_bbase2<<<2, 1024, 0, stream>>>(bsum_e, eoff, bsum_n, noff);
    k_scan_out2<<<SCB_E + SCB_N, 256, 0, stream>>>(
        tot_e, bsum_e, eoff, tot_n, bsum_n, noff);

    k_scatter_both<<<SCAT_NWG, 256, 0, stream>>>(
        V, E, re, rn, part_e, part_n, gsum_e, gsum_n,
        eoff, noff, epairs, nedges);

    k_edge_agg<<<(N_EDGES + 3) / 4, 256, 0, stream>>>(
        epairs, eoff, wexp, Xf16, S, emsg);

    k_edge_gemm<<<(N_EDGES + 63) / 64, 256, 0, stream>>>(emsg, Wtf16, Wt_b, Y16);

    k_node_agg<<<(N_NODES + 3) / 4, 256, 0, stream>>>(nedges, noff, Y16, out);
}